// Round 2
// baseline (1455.681 us; speedup 1.0000x reference)
//
#include <hip/hip_runtime.h>
#include <cstdint>

#define DI __device__ __forceinline__

// ---- problem constants (from setup_inputs: N=2e6, spatial=[480,360,32], scales=[2,4,1]) ----
constexpr int STRIDE_OUT = 18000001;   // per-scale output stride in int32 elements
constexpr int OFF_INV    = 8000000;
constexpr int OFF_COORS  = 10000000;
constexpr int OFF_NUM    = 18000000;

// dims per scale (loop order of scale_list = [2,4,1])
// scale=2: 240x180x16 ; scale=4: 120x90x8 ; scale=1: 480x360x32
// key space per scale = 8 * D0*D1*D2 (batches=8), all divisible by 32.
constexpr int RW0  = 0;         // word offset of scale-2 bitmap region
constexpr int RW1  = 172800;    // 8*240*180*16/32
constexpr int RW2  = 194400;    // + 8*120*90*8/32
constexpr int WTOT = 1576800;   // + 8*480*360*32/32
constexpr int NB1  = (WTOT + 1023) / 1024;  // scan blocks (1540)

// ---- strict (non-contractible) f32 ops so we bit-match XLA's mul,mul,add,sqrt ----
DI float fmul_s(float a, float b){ float r; asm("v_mul_f32 %0, %1, %2" : "=v"(r) : "v"(a), "v"(b)); return r; }
DI float fadd_s(float a, float b){ float r; asm("v_add_f32 %0, %1, %2" : "=v"(r) : "v"(a), "v"(b)); return r; }

DI void compute_keys(float x, float y, float z, int b, int (&key)[3], int (&g0)[3], int (&g1)[3], int (&g2)[3]) {
  const float PI_F     = 3.14159265358979323846f;  // -> 0x40490FDB (f32 pi, matches input array)
  const float TWO_PI_F = 6.28318530717958647692f;  // -> 0x40C90FDB == hi-lo exactly
  float rho = sqrtf(fadd_s(fmul_s(x, x), fmul_s(y, y)));
  float phi = atan2f(y, x);
  // t = (clip(v,lo,hi) - lo) / crop   (identical across scales, exactly as in reference)
  float tr = (fminf(fmaxf(rho, 0.0f), 50.0f) - 0.0f) / 50.0f;
  float tp = (fminf(fmaxf(phi, -PI_F), PI_F) + PI_F) / TWO_PI_F;
  float tz = (fminf(fmaxf(z, -4.0f), 2.0f) + 4.0f) / 6.0f;
  constexpr float C0[3] = {239.f, 119.f, 479.f};
  constexpr float C1[3] = {179.f,  89.f, 359.f};
  constexpr float C2[3] = { 15.f,   7.f,  31.f};
  constexpr int   D0[3] = {240, 120, 480};
  constexpr int   D1[3] = {180,  90, 360};
  constexpr int   D2[3] = { 16,   8,  32};
  #pragma unroll
  for (int s = 0; s < 3; ++s) {
    int a0 = (int)floorf(tr * C0[s]);
    int a1 = (int)floorf(tp * C1[s]);
    int a2 = (int)floorf(tz * C2[s]);
    g0[s] = a0; g1[s] = a1; g2[s] = a2;
    key[s] = ((b * D0[s] + a0) * D1[s] + a1) * D2[s] + a2;
  }
}

// ---- pass B: per point -> bxyz out + presence bits ----
// Bits are monotone 0->1, so test-before-atomic is race-safe: a stale 0 only
// causes a redundant atomicOr; a visible 1 implies the atomic already
// committed. This removes ~2/3 of the far atomics and ALL hot-line RMW storms
// (the clipped-rho last row concentrates ~430K points into a few K lines).
__global__ __launch_bounds__(256) void pass_points(const float4* __restrict__ pts,
                                                   const int* __restrict__ batch,
                                                   int n, uint32_t* __restrict__ bitmap,
                                                   int* __restrict__ out) {
  int i = blockIdx.x * 256 + threadIdx.x;
  if (i >= n) return;
  float4 p = pts[i];
  int b = batch[i];
  int key[3], g0[3], g1[3], g2[3];
  compute_keys(p.x, p.y, p.z, b, key, g0, g1, g2);
  constexpr int RW[3] = {RW0, RW1, RW2};
  #pragma unroll
  for (int s = 0; s < 3; ++s) {
    int* o = out + s * STRIDE_OUT + i * 4;
    o[0] = b; o[1] = g0[s]; o[2] = g1[s]; o[3] = g2[s];
    int w = RW[s] + (key[s] >> 5);
    uint32_t m = 1u << (key[s] & 31);
    if (!(bitmap[w] & m)) atomicOr(&bitmap[w], m);
  }
}

// ---- scan step 1: per-block popcount sums (1024 words/block) ----
__global__ __launch_bounds__(256) void scan1(const uint32_t* __restrict__ bitmap,
                                             uint32_t* __restrict__ blockSums) {
  __shared__ uint32_t lds[256];
  int t = threadIdx.x;
  int base = blockIdx.x * 1024 + t * 4;
  uint32_t s = 0;
  if (base + 4 <= WTOT) {
    uint4 w = *reinterpret_cast<const uint4*>(bitmap + base);
    s = __popc(w.x) + __popc(w.y) + __popc(w.z) + __popc(w.w);
  } else {
    for (int k = 0; k < 4; ++k) if (base + k < WTOT) s += __popc(bitmap[base + k]);
  }
  lds[t] = s; __syncthreads();
  for (int off = 128; off > 0; off >>= 1) { if (t < off) lds[t] += lds[t + off]; __syncthreads(); }
  if (t == 0) blockSums[blockIdx.x] = lds[0];
}

// ---- scan step 2: exclusive scan of block sums (single block), writes grand total ----
__global__ __launch_bounds__(256) void scan2(uint32_t* __restrict__ blockSums,
                                             uint32_t* __restrict__ prefix, int nb) {
  __shared__ uint32_t lds[256];
  int t = threadIdx.x;
  uint32_t local[7]; uint32_t sum = 0;
  #pragma unroll
  for (int k = 0; k < 7; ++k) { int idx = t * 7 + k; uint32_t v = (idx < nb) ? blockSums[idx] : 0u; local[k] = v; sum += v; }
  lds[t] = sum; __syncthreads();
  for (int off = 1; off < 256; off <<= 1) {
    uint32_t x = (t >= off) ? lds[t - off] : 0u; __syncthreads();
    lds[t] += x; __syncthreads();
  }
  uint32_t run = lds[t] - sum;  // exclusive
  #pragma unroll
  for (int k = 0; k < 7; ++k) { int idx = t * 7 + k; if (idx < nb) blockSums[idx] = run; run += local[k]; }
  if (t == 255) prefix[WTOT] = run;  // grand total bits
}

// ---- scan step 3: per-word exclusive prefix ----
__global__ __launch_bounds__(256) void scan3(const uint32_t* __restrict__ bitmap,
                                             const uint32_t* __restrict__ blockSums,
                                             uint32_t* __restrict__ prefix) {
  __shared__ uint32_t lds[256];
  int t = threadIdx.x;
  int base = blockIdx.x * 1024 + t * 4;
  uint32_t c[4]; uint32_t sum = 0;
  if (base + 4 <= WTOT) {
    uint4 w = *reinterpret_cast<const uint4*>(bitmap + base);
    c[0] = __popc(w.x); c[1] = __popc(w.y); c[2] = __popc(w.z); c[3] = __popc(w.w);
  } else {
    #pragma unroll
    for (int k = 0; k < 4; ++k) c[k] = (base + k < WTOT) ? __popc(bitmap[base + k]) : 0u;
  }
  sum = c[0] + c[1] + c[2] + c[3];
  lds[t] = sum; __syncthreads();
  for (int off = 1; off < 256; off <<= 1) {
    uint32_t x = (t >= off) ? lds[t - off] : 0u; __syncthreads();
    lds[t] += x; __syncthreads();
  }
  uint32_t excl = lds[t] - sum + blockSums[blockIdx.x];
  #pragma unroll
  for (int k = 0; k < 4; ++k) { if (base + k < WTOT) prefix[base + k] = excl; excl += c[k]; }
}

// ---- pass C: per point -> inv (rank) ----
__global__ __launch_bounds__(256) void pass_inv(const float4* __restrict__ pts,
                                                const int* __restrict__ batch, int n,
                                                const uint32_t* __restrict__ bitmap,
                                                const uint32_t* __restrict__ prefix,
                                                int* __restrict__ out) {
  int i = blockIdx.x * 256 + threadIdx.x;
  if (i >= n) return;
  float4 p = pts[i];
  int b = batch[i];
  int key[3], g0[3], g1[3], g2[3];
  compute_keys(p.x, p.y, p.z, b, key, g0, g1, g2);
  constexpr int RW[3] = {RW0, RW1, RW2};
  #pragma unroll
  for (int s = 0; s < 3; ++s) {
    int w = RW[s] + (key[s] >> 5);
    uint32_t bits = bitmap[w];
    uint32_t base = prefix[w] - prefix[RW[s]];
    int rank = (int)(base + __popc(bits & ((1u << (key[s] & 31)) - 1u)));
    out[s * STRIDE_OUT + OFF_INV + i] = rank;
  }
}

// ---- pass D: per bitmap word -> coors rows in rank order ----
template <int S>
__global__ __launch_bounds__(256) void pass_coors(const uint32_t* __restrict__ bitmap,
                                                  const uint32_t* __restrict__ prefix,
                                                  int* __restrict__ out) {
  constexpr int RW[3] = {RW0, RW1, RW2};
  constexpr int NW[3] = {RW1 - RW0, RW2 - RW1, WTOT - RW2};
  constexpr int D0[3] = {240, 120, 480};
  constexpr int D1[3] = {180,  90, 360};
  constexpr int D2[3] = { 16,   8,  32};
  int wi = blockIdx.x * 256 + threadIdx.x;
  if (wi >= NW[S]) return;
  int w = RW[S] + wi;
  uint32_t bits = bitmap[w];
  if (!bits) return;
  uint32_t rank = prefix[w] - prefix[RW[S]];
  int keybase = wi * 32;
  int* coors = out + S * STRIDE_OUT + OFF_COORS;
  while (bits) {
    int j = __builtin_ctz(bits);
    bits &= bits - 1;
    int key = keybase + j;
    int gz = key & (D2[S] - 1);
    int r  = key / D2[S];              // pow2 shift
    int q  = r / D1[S];                // magic mul (constant)
    int gy = r - q * D1[S];
    int bq = q / D0[S];
    int gx = q - bq * D0[S];
    int* o = coors + (int)rank * 4;
    o[0] = bq; o[1] = gz; o[2] = gy; o[3] = gx;   // coors = [b, z, phi, rho]
    ++rank;
  }
}

// ---- pass E: zero coors tail (dense, one dword/thread), write num ----
__global__ __launch_bounds__(256) void pass_tail(const uint32_t* __restrict__ prefix,
                                                 int* __restrict__ out, int n) {
  int s = blockIdx.y;
  int rs  = (s == 0) ? RW0 : (s == 1) ? RW1 : RW2;
  int re  = (s == 0) ? RW1 : (s == 1) ? RW2 : WTOT;
  uint32_t num = prefix[re] - prefix[rs];
  int i = blockIdx.x * 256 + threadIdx.x;     // dword index in coors region
  if (i == 0) out[s * STRIDE_OUT + OFF_NUM] = (int)num;
  if (i >= 4 * (int)num && i < 4 * n) out[s * STRIDE_OUT + OFF_COORS + i] = 0;
}

extern "C" void kernel_launch(void* const* d_in, const int* in_sizes, int n_in,
                              void* d_out, int out_size, void* d_ws, size_t ws_size,
                              hipStream_t stream) {
  const float4* pts  = (const float4*)d_in[0];
  const int*    batch = (const int*)d_in[1];
  int n = in_sizes[1];  // 2,000,000
  int* out = (int*)d_out;

  uint32_t* bitmap    = (uint32_t*)d_ws;            // WTOT words
  uint32_t* prefix    = bitmap + WTOT;              // WTOT+1 words
  uint32_t* blockSums = prefix + WTOT + 1;          // NB1 words
  // total ws use: ~12.6 MB

  hipMemsetAsync(bitmap, 0, (size_t)WTOT * sizeof(uint32_t), stream);

  int nblk = (n + 255) / 256;
  pass_points<<<nblk, 256, 0, stream>>>(pts, batch, n, bitmap, out);
  scan1<<<NB1, 256, 0, stream>>>(bitmap, blockSums);
  scan2<<<1, 256, 0, stream>>>(blockSums, prefix, NB1);
  scan3<<<NB1, 256, 0, stream>>>(bitmap, blockSums, prefix);
  pass_inv<<<nblk, 256, 0, stream>>>(pts, batch, n, bitmap, prefix, out);
  pass_coors<0><<<(RW1 - RW0 + 255) / 256, 256, 0, stream>>>(bitmap, prefix, out);
  pass_coors<1><<<(RW2 - RW1 + 255) / 256, 256, 0, stream>>>(bitmap, prefix, out);
  pass_coors<2><<<(WTOT - RW2 + 255) / 256, 256, 0, stream>>>(bitmap, prefix, out);
  dim3 gtail((unsigned)(4 * n + 255) / 256, 3);
  pass_tail<<<gtail, 256, 0, stream>>>(prefix, out, n);
}

// Round 3
// 630.198 us; speedup vs baseline: 2.3099x; 2.3099x over previous
//
#include <hip/hip_runtime.h>
#include <cstdint>

#define DI __device__ __forceinline__

// ---- problem constants (from setup_inputs: N=2e6, spatial=[480,360,32], scales=[2,4,1]) ----
constexpr int STRIDE_OUT = 18000001;   // per-scale output stride in int32 elements
constexpr int OFF_INV    = 8000000;
constexpr int OFF_COORS  = 10000000;
constexpr int OFF_NUM    = 18000000;

// scale=2: 240x180x16 ; scale=4: 120x90x8 ; scale=1: 480x360x32 ; batches=8
constexpr int R2W  = 172800;    // words, scale-2 region (8*240*180*16/32)
constexpr int R4W  = 21600;     // words, scale-4 region
constexpr int R1W  = 1382400;   // words, scale-1 region
constexpr int RW0  = 0;
constexpr int RW1  = R2W;
constexpr int RW2  = R2W + R4W;
constexpr int WTOT = R2W + R4W + R1W;       // 1576800
constexpr int NB1  = (WTOT + 1023) / 1024;  // scan blocks (1540)

// ---- strict (non-contractible) f32 ops so we bit-match XLA's mul,mul,add,sqrt ----
DI float fmul_s(float a, float b){ float r; asm("v_mul_f32 %0, %1, %2" : "=v"(r) : "v"(a), "v"(b)); return r; }
DI float fadd_s(float a, float b){ float r; asm("v_add_f32 %0, %1, %2" : "=v"(r) : "v"(a), "v"(b)); return r; }

DI void compute_keys(float x, float y, float z, int b, int (&key)[3], int (&g0)[3], int (&g1)[3], int (&g2)[3]) {
  const float PI_F     = 3.14159265358979323846f;
  const float TWO_PI_F = 6.28318530717958647692f;
  float rho = sqrtf(fadd_s(fmul_s(x, x), fmul_s(y, y)));
  float phi = atan2f(y, x);
  float tr = (fminf(fmaxf(rho, 0.0f), 50.0f) - 0.0f) / 50.0f;
  float tp = (fminf(fmaxf(phi, -PI_F), PI_F) + PI_F) / TWO_PI_F;
  float tz = (fminf(fmaxf(z, -4.0f), 2.0f) + 4.0f) / 6.0f;
  constexpr float C0[3] = {239.f, 119.f, 479.f};
  constexpr float C1[3] = {179.f,  89.f, 359.f};
  constexpr float C2[3] = { 15.f,   7.f,  31.f};
  constexpr int   D0[3] = {240, 120, 480};
  constexpr int   D1[3] = {180,  90, 360};
  constexpr int   D2[3] = { 16,   8,  32};
  #pragma unroll
  for (int s = 0; s < 3; ++s) {
    int a0 = (int)floorf(tr * C0[s]);
    int a1 = (int)floorf(tp * C1[s]);
    int a2 = (int)floorf(tz * C2[s]);
    g0[s] = a0; g1[s] = a1; g2[s] = a2;
    key[s] = ((b * D0[s] + a0) * D1[s] + a1) * D2[s] + a2;
  }
}

// ---- pass B: per point -> bxyz out + presence bits into REPLICATED regions ----
// Fire-and-forget atomics only (R2 showed test-loads ping-pong vs atomics).
// Replication spreads per-line RMW queues K ways; blockIdx&(K-1) with 8-XCD
// round-robin dispatch keeps each copy mostly single-XCD.
__global__ __launch_bounds__(256) void pass_points(const float4* __restrict__ pts,
                                                   const int* __restrict__ batch, int n,
                                                   uint32_t* __restrict__ rep2,
                                                   uint32_t* __restrict__ rep4,
                                                   uint32_t* __restrict__ rep1,
                                                   int k2m, int k4m, int k1m,
                                                   int* __restrict__ out) {
  int i = blockIdx.x * 256 + threadIdx.x;
  if (i >= n) return;
  float4 p = pts[i];
  int b = batch[i];
  int key[3], g0[3], g1[3], g2[3];
  compute_keys(p.x, p.y, p.z, b, key, g0, g1, g2);
  #pragma unroll
  for (int s = 0; s < 3; ++s) {
    int* o = out + s * STRIDE_OUT + i * 4;
    o[0] = b; o[1] = g0[s]; o[2] = g1[s]; o[3] = g2[s];
  }
  uint32_t bid = blockIdx.x;
  atomicOr(&rep2[(bid & k2m) * R2W + (key[0] >> 5)], 1u << (key[0] & 31));
  atomicOr(&rep4[(bid & k4m) * R4W + (key[1] >> 5)], 1u << (key[1] & 31));
  atomicOr(&rep1[(bid & k1m) * R1W + (key[2] >> 5)], 1u << (key[2] & 31));
}

// ---- merge: OR the K copies of one region into the canonical bitmap ----
__global__ __launch_bounds__(256) void merge_region(const uint32_t* __restrict__ rep,
                                                    uint32_t* __restrict__ dst,
                                                    int regionWords, int K) {
  int i = (blockIdx.x * 256 + threadIdx.x) * 4;     // regionWords all divisible by 4
  if (i >= regionWords) return;
  uint4 acc = make_uint4(0, 0, 0, 0);
  for (int c = 0; c < K; ++c) {
    uint4 w = *reinterpret_cast<const uint4*>(rep + (size_t)c * regionWords + i);
    acc.x |= w.x; acc.y |= w.y; acc.z |= w.z; acc.w |= w.w;
  }
  *reinterpret_cast<uint4*>(dst + i) = acc;
}

// ---- scan step 1: per-block popcount sums (1024 words/block) ----
__global__ __launch_bounds__(256) void scan1(const uint32_t* __restrict__ bitmap,
                                             uint32_t* __restrict__ blockSums) {
  __shared__ uint32_t lds[256];
  int t = threadIdx.x;
  int base = blockIdx.x * 1024 + t * 4;
  uint32_t s = 0;
  if (base + 4 <= WTOT) {
    uint4 w = *reinterpret_cast<const uint4*>(bitmap + base);
    s = __popc(w.x) + __popc(w.y) + __popc(w.z) + __popc(w.w);
  } else {
    for (int k = 0; k < 4; ++k) if (base + k < WTOT) s += __popc(bitmap[base + k]);
  }
  lds[t] = s; __syncthreads();
  for (int off = 128; off > 0; off >>= 1) { if (t < off) lds[t] += lds[t + off]; __syncthreads(); }
  if (t == 0) blockSums[blockIdx.x] = lds[0];
}

// ---- scan step 2: exclusive scan of block sums (single block), writes grand total ----
__global__ __launch_bounds__(256) void scan2(uint32_t* __restrict__ blockSums,
                                             uint32_t* __restrict__ prefix, int nb) {
  __shared__ uint32_t lds[256];
  int t = threadIdx.x;
  uint32_t local[7]; uint32_t sum = 0;
  #pragma unroll
  for (int k = 0; k < 7; ++k) { int idx = t * 7 + k; uint32_t v = (idx < nb) ? blockSums[idx] : 0u; local[k] = v; sum += v; }
  lds[t] = sum; __syncthreads();
  for (int off = 1; off < 256; off <<= 1) {
    uint32_t x = (t >= off) ? lds[t - off] : 0u; __syncthreads();
    lds[t] += x; __syncthreads();
  }
  uint32_t run = lds[t] - sum;  // exclusive
  #pragma unroll
  for (int k = 0; k < 7; ++k) { int idx = t * 7 + k; if (idx < nb) blockSums[idx] = run; run += local[k]; }
  if (t == 255) prefix[WTOT] = run;
}

// ---- scan step 3: per-word exclusive prefix ----
__global__ __launch_bounds__(256) void scan3(const uint32_t* __restrict__ bitmap,
                                             const uint32_t* __restrict__ blockSums,
                                             uint32_t* __restrict__ prefix) {
  __shared__ uint32_t lds[256];
  int t = threadIdx.x;
  int base = blockIdx.x * 1024 + t * 4;
  uint32_t c[4]; uint32_t sum = 0;
  if (base + 4 <= WTOT) {
    uint4 w = *reinterpret_cast<const uint4*>(bitmap + base);
    c[0] = __popc(w.x); c[1] = __popc(w.y); c[2] = __popc(w.z); c[3] = __popc(w.w);
  } else {
    #pragma unroll
    for (int k = 0; k < 4; ++k) c[k] = (base + k < WTOT) ? __popc(bitmap[base + k]) : 0u;
  }
  sum = c[0] + c[1] + c[2] + c[3];
  lds[t] = sum; __syncthreads();
  for (int off = 1; off < 256; off <<= 1) {
    uint32_t x = (t >= off) ? lds[t - off] : 0u; __syncthreads();
    lds[t] += x; __syncthreads();
  }
  uint32_t excl = lds[t] - sum + blockSums[blockIdx.x];
  #pragma unroll
  for (int k = 0; k < 4; ++k) { if (base + k < WTOT) prefix[base + k] = excl; excl += c[k]; }
}

// ---- pass C: per point -> inv (rank) ----
__global__ __launch_bounds__(256) void pass_inv(const float4* __restrict__ pts,
                                                const int* __restrict__ batch, int n,
                                                const uint32_t* __restrict__ bitmap,
                                                const uint32_t* __restrict__ prefix,
                                                int* __restrict__ out) {
  int i = blockIdx.x * 256 + threadIdx.x;
  if (i >= n) return;
  float4 p = pts[i];
  int b = batch[i];
  int key[3], g0[3], g1[3], g2[3];
  compute_keys(p.x, p.y, p.z, b, key, g0, g1, g2);
  constexpr int RW[3] = {RW0, RW1, RW2};
  #pragma unroll
  for (int s = 0; s < 3; ++s) {
    int w = RW[s] + (key[s] >> 5);
    uint32_t bits = bitmap[w];
    uint32_t base = prefix[w] - prefix[RW[s]];
    int rank = (int)(base + __popc(bits & ((1u << (key[s] & 31)) - 1u)));
    out[s * STRIDE_OUT + OFF_INV + i] = rank;
  }
}

// ---- pass D: per bitmap word -> coors rows in rank order ----
template <int S>
__global__ __launch_bounds__(256) void pass_coors(const uint32_t* __restrict__ bitmap,
                                                  const uint32_t* __restrict__ prefix,
                                                  int* __restrict__ out) {
  constexpr int RW[3] = {RW0, RW1, RW2};
  constexpr int NW[3] = {R2W, R4W, R1W};
  constexpr int D0[3] = {240, 120, 480};
  constexpr int D1[3] = {180,  90, 360};
  constexpr int D2[3] = { 16,   8,  32};
  int wi = blockIdx.x * 256 + threadIdx.x;
  if (wi >= NW[S]) return;
  int w = RW[S] + wi;
  uint32_t bits = bitmap[w];
  if (!bits) return;
  uint32_t rank = prefix[w] - prefix[RW[S]];
  int keybase = wi * 32;
  int* coors = out + S * STRIDE_OUT + OFF_COORS;
  while (bits) {
    int j = __builtin_ctz(bits);
    bits &= bits - 1;
    int key = keybase + j;
    int gz = key & (D2[S] - 1);
    int r  = key / D2[S];
    int q  = r / D1[S];
    int gy = r - q * D1[S];
    int bq = q / D0[S];
    int gx = q - bq * D0[S];
    int* o = coors + (int)rank * 4;
    o[0] = bq; o[1] = gz; o[2] = gy; o[3] = gx;   // coors = [b, z, phi, rho]
    ++rank;
  }
}

// ---- pass E: zero coors tail (dense, one dword/thread), write num ----
__global__ __launch_bounds__(256) void pass_tail(const uint32_t* __restrict__ prefix,
                                                 int* __restrict__ out, int n) {
  int s = blockIdx.y;
  int rs  = (s == 0) ? RW0 : (s == 1) ? RW1 : RW2;
  int re  = (s == 0) ? RW1 : (s == 1) ? RW2 : WTOT;
  uint32_t num = prefix[re] - prefix[rs];
  int i = blockIdx.x * 256 + threadIdx.x;
  if (i == 0) out[s * STRIDE_OUT + OFF_NUM] = (int)num;
  if (i >= 4 * (int)num && i < 4 * n) out[s * STRIDE_OUT + OFF_COORS + i] = 0;
}

extern "C" void kernel_launch(void* const* d_in, const int* in_sizes, int n_in,
                              void* d_out, int out_size, void* d_ws, size_t ws_size,
                              hipStream_t stream) {
  const float4* pts   = (const float4*)d_in[0];
  const int*    batch = (const int*)d_in[1];
  int n = in_sizes[1];  // 2,000,000
  int* out = (int*)d_out;

  // pick replication factors that fit ws_size (deterministic: ws_size is fixed)
  static const int KOPT[6][3] = {{16,16,4},{8,16,4},{8,8,2},{4,4,2},{2,2,1},{1,1,1}};
  size_t fixed_words = (size_t)WTOT /*bitmap*/ + (size_t)(WTOT + 1) /*prefix*/ + NB1 + 64;
  int K2 = 1, K4 = 1, K1 = 1;
  for (int c = 0; c < 6; ++c) {
    size_t rep_words = (size_t)KOPT[c][0] * R2W + (size_t)KOPT[c][1] * R4W + (size_t)KOPT[c][2] * R1W;
    if ((fixed_words + rep_words) * 4 <= ws_size) { K2 = KOPT[c][0]; K4 = KOPT[c][1]; K1 = KOPT[c][2]; break; }
  }
  size_t rep_words = (size_t)K2 * R2W + (size_t)K4 * R4W + (size_t)K1 * R1W;

  uint32_t* rep2      = (uint32_t*)d_ws;
  uint32_t* rep4      = rep2 + (size_t)K2 * R2W;
  uint32_t* rep1      = rep4 + (size_t)K4 * R4W;
  uint32_t* bitmap    = rep1 + (size_t)K1 * R1W;
  uint32_t* prefix    = bitmap + WTOT;
  uint32_t* blockSums = prefix + WTOT + 1;

  hipMemsetAsync(rep2, 0, rep_words * sizeof(uint32_t), stream);

  int nblk = (n + 255) / 256;
  pass_points<<<nblk, 256, 0, stream>>>(pts, batch, n, rep2, rep4, rep1,
                                        K2 - 1, K4 - 1, K1 - 1, out);
  merge_region<<<(R2W / 4 + 255) / 256, 256, 0, stream>>>(rep2, bitmap + RW0, R2W, K2);
  merge_region<<<(R4W / 4 + 255) / 256, 256, 0, stream>>>(rep4, bitmap + RW1, R4W, K4);
  merge_region<<<(R1W / 4 + 255) / 256, 256, 0, stream>>>(rep1, bitmap + RW2, R1W, K1);
  scan1<<<NB1, 256, 0, stream>>>(bitmap, blockSums);
  scan2<<<1, 256, 0, stream>>>(blockSums, prefix, NB1);
  scan3<<<NB1, 256, 0, stream>>>(bitmap, blockSums, prefix);
  pass_inv<<<nblk, 256, 0, stream>>>(pts, batch, n, bitmap, prefix, out);
  pass_coors<0><<<(R2W + 255) / 256, 256, 0, stream>>>(bitmap, prefix, out);
  pass_coors<1><<<(R4W + 255) / 256, 256, 0, stream>>>(bitmap, prefix, out);
  pass_coors<2><<<(R1W + 255) / 256, 256, 0, stream>>>(bitmap, prefix, out);
  dim3 gtail((unsigned)((4 * n + 255) / 256), 3);
  pass_tail<<<gtail, 256, 0, stream>>>(prefix, out, n);
}

// Round 4
// 552.588 us; speedup vs baseline: 2.6343x; 1.1404x over previous
//
#include <hip/hip_runtime.h>
#include <cstdint>

#define DI __device__ __forceinline__

// ---- problem constants (from setup_inputs: N=2e6, spatial=[480,360,32], scales=[2,4,1]) ----
constexpr int STRIDE_OUT = 18000001;   // per-scale output stride in int32 elements
constexpr int OFF_INV    = 8000000;
constexpr int OFF_COORS  = 10000000;
constexpr int OFF_NUM    = 18000000;

// scale=2: 240x180x16 ; scale=4: 120x90x8 ; scale=1: 480x360x32 ; batches=8
constexpr int R2W  = 172800;    // words, scale-2 region
constexpr int R4W  = 21600;     // words, scale-4 region (86.4 KB -> fits in LDS!)
constexpr int R1W  = 1382400;   // words, scale-1 region
constexpr int RW0  = 0;
constexpr int RW1  = R2W;
constexpr int RW2  = R2W + R4W;
constexpr int WTOT = R2W + R4W + R1W;       // 1576800
constexpr int NB1  = (WTOT + 1023) / 1024;  // scan blocks (1540)

// ---- strict (non-contractible) f32 ops so we bit-match XLA's mul,mul,add,sqrt ----
DI float fmul_s(float a, float b){ float r; asm("v_mul_f32 %0, %1, %2" : "=v"(r) : "v"(a), "v"(b)); return r; }
DI float fadd_s(float a, float b){ float r; asm("v_add_f32 %0, %1, %2" : "=v"(r) : "v"(a), "v"(b)); return r; }

DI void compute_keys(float x, float y, float z, int b, int (&key)[3], int (&g0)[3], int (&g1)[3], int (&g2)[3]) {
  const float PI_F     = 3.14159265358979323846f;
  const float TWO_PI_F = 6.28318530717958647692f;
  float rho = sqrtf(fadd_s(fmul_s(x, x), fmul_s(y, y)));
  float phi = atan2f(y, x);
  float tr = (fminf(fmaxf(rho, 0.0f), 50.0f) - 0.0f) / 50.0f;
  float tp = (fminf(fmaxf(phi, -PI_F), PI_F) + PI_F) / TWO_PI_F;
  float tz = (fminf(fmaxf(z, -4.0f), 2.0f) + 4.0f) / 6.0f;
  constexpr float C0[3] = {239.f, 119.f, 479.f};
  constexpr float C1[3] = {179.f,  89.f, 359.f};
  constexpr float C2[3] = { 15.f,   7.f,  31.f};
  constexpr int   D0[3] = {240, 120, 480};
  constexpr int   D1[3] = {180,  90, 360};
  constexpr int   D2[3] = { 16,   8,  32};
  #pragma unroll
  for (int s = 0; s < 3; ++s) {
    int a0 = (int)floorf(tr * C0[s]);
    int a1 = (int)floorf(tp * C1[s]);
    int a2 = (int)floorf(tz * C2[s]);
    g0[s] = a0; g1[s] = a1; g2[s] = a2;
    key[s] = ((b * D0[s] + a0) * D1[s] + a1) * D2[s] + a2;
  }
}

// ---- pass B: per point -> bxyz + keys + atomics (scale-2, scale-1 only) ----
__global__ __launch_bounds__(256) void pass_points(const float4* __restrict__ pts,
                                                   const int* __restrict__ batch, int n,
                                                   uint32_t* __restrict__ rep2,
                                                   uint32_t* __restrict__ rep1,
                                                   int k2m, int k1m,
                                                   int* __restrict__ keys,  // 3*n or null
                                                   int* __restrict__ out) {
  int i = blockIdx.x * 256 + threadIdx.x;
  if (i >= n) return;
  float4 p = pts[i];
  int b = batch[i];
  int key[3], g0[3], g1[3], g2[3];
  compute_keys(p.x, p.y, p.z, b, key, g0, g1, g2);
  #pragma unroll
  for (int s = 0; s < 3; ++s) {
    int4 v = make_int4(b, g0[s], g1[s], g2[s]);
    *reinterpret_cast<int4*>(out + s * STRIDE_OUT + i * 4) = v;
  }
  if (keys) {
    keys[i] = key[0]; keys[n + i] = key[1]; keys[2 * n + i] = key[2];
  }
  uint32_t bid = blockIdx.x;
  atomicOr(&rep2[(bid & k2m) * R2W + (key[0] >> 5)], 1u << (key[0] & 31));
  atomicOr(&rep1[(bid & k1m) * R1W + (key[2] >> 5)], 1u << (key[2] & 31));
}

// ---- hist4: full scale-4 bitmap in LDS per block; flush nonzero words ----
// 2M device atomics -> ~64*2700 = 173K flush atomics. Points sorted by batch
// => each block's chunk spans ~1 batch window (2700 words), so nonzero words
// per block ~= 2700 regardless of chunk size.
__global__ __launch_bounds__(1024) void hist4(const float4* __restrict__ pts,
                                              const int* __restrict__ batch,
                                              const int* __restrict__ keys, int n,
                                              uint32_t* __restrict__ rep4, int k4m) {
  __shared__ uint32_t bm[R4W];
  int t = threadIdx.x;
  for (int w = t; w < R4W; w += 1024) bm[w] = 0;
  __syncthreads();
  int chunk = (n + gridDim.x - 1) / gridDim.x;
  int start = blockIdx.x * chunk;
  int end = min(start + chunk, n);
  if (keys) {
    const int* k1 = keys + n;
    for (int i = start + t; i < end; i += 1024) {
      int key = k1[i];
      atomicOr(&bm[key >> 5], 1u << (key & 31));
    }
  } else {
    for (int i = start + t; i < end; i += 1024) {
      float4 p = pts[i];
      int key[3], g0[3], g1[3], g2[3];
      compute_keys(p.x, p.y, p.z, batch[i], key, g0, g1, g2);
      atomicOr(&bm[key[1] >> 5], 1u << (key[1] & 31));
    }
  }
  __syncthreads();
  uint32_t c = blockIdx.x & k4m;
  for (int w = t; w < R4W; w += 1024) {
    uint32_t v = bm[w];
    if (v) atomicOr(&rep4[c * R4W + w], v);
  }
}

// ---- merge: OR the K copies of one region into the canonical bitmap ----
__global__ __launch_bounds__(256) void merge_region(const uint32_t* __restrict__ rep,
                                                    uint32_t* __restrict__ dst,
                                                    int regionWords, int K) {
  int i = (blockIdx.x * 256 + threadIdx.x) * 4;
  if (i >= regionWords) return;
  uint4 acc = make_uint4(0, 0, 0, 0);
  for (int c = 0; c < K; ++c) {
    uint4 w = *reinterpret_cast<const uint4*>(rep + (size_t)c * regionWords + i);
    acc.x |= w.x; acc.y |= w.y; acc.z |= w.z; acc.w |= w.w;
  }
  *reinterpret_cast<uint4*>(dst + i) = acc;
}

// ---- scan step 1: per-block popcount sums (1024 words/block) ----
__global__ __launch_bounds__(256) void scan1(const uint32_t* __restrict__ bitmap,
                                             uint32_t* __restrict__ blockSums) {
  __shared__ uint32_t lds[256];
  int t = threadIdx.x;
  int base = blockIdx.x * 1024 + t * 4;
  uint32_t s = 0;
  if (base + 4 <= WTOT) {
    uint4 w = *reinterpret_cast<const uint4*>(bitmap + base);
    s = __popc(w.x) + __popc(w.y) + __popc(w.z) + __popc(w.w);
  } else {
    for (int k = 0; k < 4; ++k) if (base + k < WTOT) s += __popc(bitmap[base + k]);
  }
  lds[t] = s; __syncthreads();
  for (int off = 128; off > 0; off >>= 1) { if (t < off) lds[t] += lds[t + off]; __syncthreads(); }
  if (t == 0) blockSums[blockIdx.x] = lds[0];
}

// ---- scan step 2: exclusive scan of block sums; totals[0] = grand total ----
__global__ __launch_bounds__(256) void scan2(uint32_t* __restrict__ blockSums,
                                             uint32_t* __restrict__ totals, int nb) {
  __shared__ uint32_t lds[256];
  int t = threadIdx.x;
  uint32_t local[7]; uint32_t sum = 0;
  #pragma unroll
  for (int k = 0; k < 7; ++k) { int idx = t * 7 + k; uint32_t v = (idx < nb) ? blockSums[idx] : 0u; local[k] = v; sum += v; }
  lds[t] = sum; __syncthreads();
  for (int off = 1; off < 256; off <<= 1) {
    uint32_t x = (t >= off) ? lds[t - off] : 0u; __syncthreads();
    lds[t] += x; __syncthreads();
  }
  uint32_t run = lds[t] - sum;
  #pragma unroll
  for (int k = 0; k < 7; ++k) { int idx = t * 7 + k; if (idx < nb) blockSums[idx] = run; run += local[k]; }
  if (t == 255) totals[0] = run;
}

// ---- scan step 3: per-word (bits, exclusive-prefix) pairs ----
__global__ __launch_bounds__(256) void scan3(const uint32_t* __restrict__ bitmap,
                                             const uint32_t* __restrict__ blockSums,
                                             uint2* __restrict__ pairs) {
  __shared__ uint32_t lds[256];
  int t = threadIdx.x;
  int base = blockIdx.x * 1024 + t * 4;
  uint32_t b[4]; uint32_t c[4]; uint32_t sum = 0;
  if (base + 4 <= WTOT) {
    uint4 w = *reinterpret_cast<const uint4*>(bitmap + base);
    b[0] = w.x; b[1] = w.y; b[2] = w.z; b[3] = w.w;
  } else {
    #pragma unroll
    for (int k = 0; k < 4; ++k) b[k] = (base + k < WTOT) ? bitmap[base + k] : 0u;
  }
  #pragma unroll
  for (int k = 0; k < 4; ++k) { c[k] = __popc(b[k]); sum += c[k]; }
  lds[t] = sum; __syncthreads();
  for (int off = 1; off < 256; off <<= 1) {
    uint32_t x = (t >= off) ? lds[t - off] : 0u; __syncthreads();
    lds[t] += x; __syncthreads();
  }
  uint32_t excl = lds[t] - sum + blockSums[blockIdx.x];
  #pragma unroll
  for (int k = 0; k < 4; ++k) {
    if (base + k < WTOT) pairs[base + k] = make_uint2(b[k], excl);
    excl += c[k];
  }
}

// ---- pass C: per point -> inv (rank); single 8B gather per scale ----
__global__ __launch_bounds__(256) void pass_inv(const float4* __restrict__ pts,
                                                const int* __restrict__ batch, int n,
                                                const uint2* __restrict__ pairs,
                                                const int* __restrict__ keys,  // or null
                                                int* __restrict__ out) {
  int i = blockIdx.x * 256 + threadIdx.x;
  if (i >= n) return;
  int key[3];
  if (keys) {
    key[0] = keys[i]; key[1] = keys[n + i]; key[2] = keys[2 * n + i];
  } else {
    int g0[3], g1[3], g2[3];
    float4 p = pts[i];
    compute_keys(p.x, p.y, p.z, batch[i], key, g0, g1, g2);
  }
  constexpr int RW[3] = {RW0, RW1, RW2};
  #pragma unroll
  for (int s = 0; s < 3; ++s) {
    uint2 pr = pairs[RW[s] + (key[s] >> 5)];
    uint32_t base = pr.y - ((s == 0) ? 0u : pairs[RW[s]].y);
    int rank = (int)(base + __popc(pr.x & ((1u << (key[s] & 31)) - 1u)));
    out[s * STRIDE_OUT + OFF_INV + i] = rank;
  }
}

// ---- pass D: per bitmap word -> coors rows in rank order ----
template <int S>
__global__ __launch_bounds__(256) void pass_coors(const uint2* __restrict__ pairs,
                                                  int* __restrict__ out) {
  constexpr int RW[3] = {RW0, RW1, RW2};
  constexpr int NW[3] = {R2W, R4W, R1W};
  constexpr int D0[3] = {240, 120, 480};
  constexpr int D1[3] = {180,  90, 360};
  constexpr int D2[3] = { 16,   8,  32};
  int wi = blockIdx.x * 256 + threadIdx.x;
  if (wi >= NW[S]) return;
  uint2 pr = pairs[RW[S] + wi];
  uint32_t bits = pr.x;
  if (!bits) return;
  uint32_t rank = pr.y - ((S == 0) ? 0u : pairs[RW[S]].y);
  int keybase = wi * 32;
  int* coors = out + S * STRIDE_OUT + OFF_COORS;
  while (bits) {
    int j = __builtin_ctz(bits);
    bits &= bits - 1;
    int key = keybase + j;
    int gz = key & (D2[S] - 1);
    int r  = key / D2[S];
    int q  = r / D1[S];
    int gy = r - q * D1[S];
    int bq = q / D0[S];
    int gx = q - bq * D0[S];
    *reinterpret_cast<int4*>(coors + (size_t)rank * 4) = make_int4(bq, gz, gy, gx);
    ++rank;
  }
}

// ---- pass E: zero coors tail (dense, one dword/thread), write num ----
__global__ __launch_bounds__(256) void pass_tail(const uint2* __restrict__ pairs,
                                                 const uint32_t* __restrict__ totals,
                                                 int* __restrict__ out, int n) {
  int s = blockIdx.y;
  uint32_t lo = (s == 0) ? 0u : pairs[(s == 1) ? RW1 : RW2].y;
  uint32_t hi = (s == 0) ? pairs[RW1].y : (s == 1) ? pairs[RW2].y : totals[0];
  uint32_t num = hi - lo;
  int i = blockIdx.x * 256 + threadIdx.x;
  if (i == 0) out[s * STRIDE_OUT + OFF_NUM] = (int)num;
  if (i >= 4 * (int)num && i < 4 * n) out[s * STRIDE_OUT + OFF_COORS + i] = 0;
}

extern "C" void kernel_launch(void* const* d_in, const int* in_sizes, int n_in,
                              void* d_out, int out_size, void* d_ws, size_t ws_size,
                              hipStream_t stream) {
  const float4* pts   = (const float4*)d_in[0];
  const int*    batch = (const int*)d_in[1];
  int n = in_sizes[1];  // 2,000,000
  int* out = (int*)d_out;

  // Layout ladder: reps | bitmap | pairs | blockSums | totals | keys?
  // Deterministic in ws_size -> graph-safe.
  struct Cfg { int k2, k4, k1, useKeys; };
  static const Cfg CFG[7] = {{32,16,8,1},{16,16,8,1},{16,16,4,1},{16,16,4,0},
                             {8,8,2,0},{2,2,1,0},{1,1,1,0}};
  size_t fixed_words = (size_t)WTOT + 2 * (size_t)WTOT + NB1 + 16;
  Cfg cfg = CFG[6];
  for (int c = 0; c < 7; ++c) {
    size_t w = fixed_words + (size_t)CFG[c].k2 * R2W + (size_t)CFG[c].k4 * R4W +
               (size_t)CFG[c].k1 * R1W + (CFG[c].useKeys ? (size_t)3 * n : 0);
    if (w * 4 <= ws_size) { cfg = CFG[c]; break; }
  }
  size_t rep_words = (size_t)cfg.k2 * R2W + (size_t)cfg.k4 * R4W + (size_t)cfg.k1 * R1W;

  uint32_t* rep2      = (uint32_t*)d_ws;
  uint32_t* rep4      = rep2 + (size_t)cfg.k2 * R2W;
  uint32_t* rep1      = rep4 + (size_t)cfg.k4 * R4W;
  uint32_t* bitmap    = rep1 + (size_t)cfg.k1 * R1W;
  uint2*    pairs     = (uint2*)(bitmap + WTOT);
  uint32_t* blockSums = (uint32_t*)(pairs + WTOT);
  uint32_t* totals    = blockSums + NB1;
  int*      keys      = cfg.useKeys ? (int*)(totals + 16) : nullptr;

  hipMemsetAsync(rep2, 0, rep_words * sizeof(uint32_t), stream);

  int nblk = (n + 255) / 256;
  pass_points<<<nblk, 256, 0, stream>>>(pts, batch, n, rep2, rep1,
                                        cfg.k2 - 1, cfg.k1 - 1, keys, out);
  hist4<<<64, 1024, 0, stream>>>(pts, batch, keys, n, rep4, cfg.k4 - 1);
  merge_region<<<(R2W / 4 + 255) / 256, 256, 0, stream>>>(rep2, bitmap + RW0, R2W, cfg.k2);
  merge_region<<<(R4W / 4 + 255) / 256, 256, 0, stream>>>(rep4, bitmap + RW1, R4W, cfg.k4);
  merge_region<<<(R1W / 4 + 255) / 256, 256, 0, stream>>>(rep1, bitmap + RW2, R1W, cfg.k1);
  scan1<<<NB1, 256, 0, stream>>>(bitmap, blockSums);
  scan2<<<1, 256, 0, stream>>>(blockSums, totals, NB1);
  scan3<<<NB1, 256, 0, stream>>>(bitmap, blockSums, pairs);
  pass_inv<<<nblk, 256, 0, stream>>>(pts, batch, n, pairs, keys, out);
  pass_coors<0><<<(R2W + 255) / 256, 256, 0, stream>>>(pairs, out);
  pass_coors<1><<<(R4W + 255) / 256, 256, 0, stream>>>(pairs, out);
  pass_coors<2><<<(R1W + 255) / 256, 256, 0, stream>>>(pairs, out);
  dim3 gtail((unsigned)((4 * n + 255) / 256), 3);
  pass_tail<<<gtail, 256, 0, stream>>>(pairs, totals, out, n);
}

// Round 5
// 416.009 us; speedup vs baseline: 3.4992x; 1.3283x over previous
//
#include <hip/hip_runtime.h>
#include <cstdint>

#define DI __device__ __forceinline__

// ---- problem constants (from setup_inputs: N=2e6, spatial=[480,360,32], scales=[2,4,1]) ----
constexpr int STRIDE_OUT = 18000001;   // per-scale output stride in int32 elements
constexpr int OFF_INV    = 8000000;
constexpr int OFF_COORS  = 10000000;
constexpr int OFF_NUM    = 18000000;

// scale=2: 240x180x16 ; scale=4: 120x90x8 ; scale=1: 480x360x32 ; batches=8 (sorted!)
constexpr int R2W  = 172800;    // words, scale-2 region; per-batch slice 21600 w (86.4 KB, fits LDS)
constexpr int R4W  = 21600;     // words, scale-4 region; per-batch slice 2700 w (10.8 KB)
constexpr int R1W  = 1382400;   // words, scale-1 region; per-(batch,rho/8) slice 21600 w
constexpr int RW0  = 0;
constexpr int RW1  = R2W;
constexpr int RW2  = R2W + R4W;
constexpr int WTOT = R2W + R4W + R1W;       // 1576800
constexpr int NB1  = (WTOT + 1023) / 1024;  // scan blocks (1540)
constexpr int J2   = 8;                     // sub-chunk copies, scale-2/4

// ---- strict (non-contractible) f32 ops so we bit-match XLA's mul,mul,add,sqrt ----
DI float fmul_s(float a, float b){ float r; asm("v_mul_f32 %0, %1, %2" : "=v"(r) : "v"(a), "v"(b)); return r; }
DI float fadd_s(float a, float b){ float r; asm("v_add_f32 %0, %1, %2" : "=v"(r) : "v"(a), "v"(b)); return r; }

DI void compute_keys(float x, float y, float z, int b, int (&key)[3], int (&g0)[3], int (&g1)[3], int (&g2)[3]) {
  const float PI_F     = 3.14159265358979323846f;
  const float TWO_PI_F = 6.28318530717958647692f;
  float rho = sqrtf(fadd_s(fmul_s(x, x), fmul_s(y, y)));
  float phi = atan2f(y, x);
  float tr = (fminf(fmaxf(rho, 0.0f), 50.0f) - 0.0f) / 50.0f;
  float tp = (fminf(fmaxf(phi, -PI_F), PI_F) + PI_F) / TWO_PI_F;
  float tz = (fminf(fmaxf(z, -4.0f), 2.0f) + 4.0f) / 6.0f;
  constexpr float C0[3] = {239.f, 119.f, 479.f};
  constexpr float C1[3] = {179.f,  89.f, 359.f};
  constexpr float C2[3] = { 15.f,   7.f,  31.f};
  constexpr int   D0[3] = {240, 120, 480};
  constexpr int   D1[3] = {180,  90, 360};
  constexpr int   D2[3] = { 16,   8,  32};
  #pragma unroll
  for (int s = 0; s < 3; ++s) {
    int a0 = (int)floorf(tr * C0[s]);
    int a1 = (int)floorf(tp * C1[s]);
    int a2 = (int)floorf(tz * C2[s]);
    g0[s] = a0; g1[s] = a1; g2[s] = a2;
    key[s] = ((b * D0[s] + a0) * D1[s] + a1) * D2[s] + a2;
  }
}

DI int lower_bound(const int* __restrict__ a, int n, int v) {
  int lo = 0, hi = n;
  while (lo < hi) { int m = (lo + hi) >> 1; if (a[m] < v) lo = m + 1; else hi = m; }
  return lo;
}

// ---- pass B: per point -> bxyz + keys. ZERO atomics. ----
__global__ __launch_bounds__(256) void pass_points(const float4* __restrict__ pts,
                                                   const int* __restrict__ batch, int n,
                                                   int* __restrict__ keys,
                                                   int* __restrict__ out) {
  int i = blockIdx.x * 256 + threadIdx.x;
  if (i >= n) return;
  float4 p = pts[i];
  int b = batch[i];
  int key[3], g0[3], g1[3], g2[3];
  compute_keys(p.x, p.y, p.z, b, key, g0, g1, g2);
  #pragma unroll
  for (int s = 0; s < 3; ++s) {
    *reinterpret_cast<int4*>(out + s * STRIDE_OUT + i * 4) = make_int4(b, g0[s], g1[s], g2[s]);
  }
  keys[i] = key[0]; keys[n + i] = key[1]; keys[2 * n + i] = key[2];
}

// ---- hist24: LDS histogram for scale-2 + scale-4, per (batch, subchunk) block ----
// Block (bv, j): full per-batch slices in LDS, plain-store flush to copy j.
// Every word of rep2s/rep4s is written (zeros included) -> no memset needed.
__global__ __launch_bounds__(1024) void hist24(const int* __restrict__ batch,
                                               const int* __restrict__ keys, int n,
                                               uint32_t* __restrict__ rep2s,
                                               uint32_t* __restrict__ rep4s) {
  alignas(16) __shared__ uint32_t bm2[21600];
  alignas(16) __shared__ uint32_t bm4[2700];
  int t = threadIdx.x;
  int bv = blockIdx.x >> 3, j = blockIdx.x & 7;
  for (int w = t * 4; w < 21600; w += 4096) *reinterpret_cast<uint4*>(bm2 + w) = make_uint4(0,0,0,0);
  for (int w = t; w < 2700; w += 1024) bm4[w] = 0;
  __syncthreads();
  int lo = lower_bound(batch, n, bv);
  int hi = lower_bound(batch, n, bv + 1);
  int sz = hi - lo;
  int s = lo + (int)((long long)sz * j / J2);
  int e = lo + (int)((long long)sz * (j + 1) / J2);
  const int* k0 = keys;
  const int* k1 = keys + n;
  for (int i = s + t; i < e; i += 1024) {
    int ink2 = k0[i] - bv * 691200;   // 240*180*16 bits/batch
    int ink4 = k1[i] - bv * 86400;    // 120*90*8 bits/batch
    atomicOr(&bm2[ink2 >> 5], 1u << (ink2 & 31));
    atomicOr(&bm4[ink4 >> 5], 1u << (ink4 & 31));
  }
  __syncthreads();
  uint32_t* d2 = rep2s + (size_t)j * R2W + bv * 21600;
  uint32_t* d4 = rep4s + (size_t)j * R4W + bv * 2700;
  for (int w = t * 4; w < 21600; w += 4096) *reinterpret_cast<uint4*>(d2 + w) = *reinterpret_cast<uint4*>(bm2 + w);
  for (int w = t * 4; w < 2700; w += 4096) *reinterpret_cast<uint4*>(d4 + w) = *reinterpret_cast<uint4*>(bm4 + w);  // 2700%4==3? no: 2700/4=675 exact
}

// ---- hist1: scale-1 via 8-way rho partition; block (bv, r, j) ----
__global__ __launch_bounds__(1024) void hist1(const int* __restrict__ batch,
                                              const int* __restrict__ keys, int n,
                                              uint32_t* __restrict__ rep1s, int j1) {
  alignas(16) __shared__ uint32_t bm[21600];
  int t = threadIdx.x;
  int j = blockIdx.x >> 6;
  int slice = blockIdx.x & 63;        // bv*8 + r
  int bv = slice >> 3, r = slice & 7;
  for (int w = t * 4; w < 21600; w += 4096) *reinterpret_cast<uint4*>(bm + w) = make_uint4(0,0,0,0);
  __syncthreads();
  int lo = lower_bound(batch, n, bv);
  int hi = lower_bound(batch, n, bv + 1);
  int sz = hi - lo;
  int s = lo + (int)((long long)sz * j / j1);
  int e = lo + (int)((long long)sz * (j + 1) / j1);
  const int* k2 = keys + 2 * n;
  int base = bv * 5529600 + r * 691200;   // this block's bit-range start
  for (int i = s + t; i < e; i += 1024) {
    int rel = k2[i] - base;               // in [0, 691200) iff in our rho range
    if ((unsigned)rel < 691200u) atomicOr(&bm[rel >> 5], 1u << (rel & 31));
  }
  __syncthreads();
  uint32_t* d = rep1s + (size_t)j * R1W + (size_t)slice * 21600;
  for (int w = t * 4; w < 21600; w += 4096) *reinterpret_cast<uint4*>(d + w) = *reinterpret_cast<uint4*>(bm + w);
}

// ---- merge: OR the K copies of one region into the canonical bitmap ----
__global__ __launch_bounds__(256) void merge_region(const uint32_t* __restrict__ rep,
                                                    uint32_t* __restrict__ dst,
                                                    int regionWords, int K) {
  int i = (blockIdx.x * 256 + threadIdx.x) * 4;
  if (i >= regionWords) return;
  uint4 acc = make_uint4(0, 0, 0, 0);
  for (int c = 0; c < K; ++c) {
    uint4 w = *reinterpret_cast<const uint4*>(rep + (size_t)c * regionWords + i);
    acc.x |= w.x; acc.y |= w.y; acc.z |= w.z; acc.w |= w.w;
  }
  *reinterpret_cast<uint4*>(dst + i) = acc;
}

// ---- scan step 1: per-block popcount sums (1024 words/block) ----
__global__ __launch_bounds__(256) void scan1(const uint32_t* __restrict__ bitmap,
                                             uint32_t* __restrict__ blockSums) {
  __shared__ uint32_t lds[256];
  int t = threadIdx.x;
  int base = blockIdx.x * 1024 + t * 4;
  uint32_t s = 0;
  if (base + 4 <= WTOT) {
    uint4 w = *reinterpret_cast<const uint4*>(bitmap + base);
    s = __popc(w.x) + __popc(w.y) + __popc(w.z) + __popc(w.w);
  } else {
    for (int k = 0; k < 4; ++k) if (base + k < WTOT) s += __popc(bitmap[base + k]);
  }
  lds[t] = s; __syncthreads();
  for (int off = 128; off > 0; off >>= 1) { if (t < off) lds[t] += lds[t + off]; __syncthreads(); }
  if (t == 0) blockSums[blockIdx.x] = lds[0];
}

// ---- scan step 2: exclusive scan of block sums; totals[0] = grand total ----
__global__ __launch_bounds__(256) void scan2(uint32_t* __restrict__ blockSums,
                                             uint32_t* __restrict__ totals, int nb) {
  __shared__ uint32_t lds[256];
  int t = threadIdx.x;
  uint32_t local[7]; uint32_t sum = 0;
  #pragma unroll
  for (int k = 0; k < 7; ++k) { int idx = t * 7 + k; uint32_t v = (idx < nb) ? blockSums[idx] : 0u; local[k] = v; sum += v; }
  lds[t] = sum; __syncthreads();
  for (int off = 1; off < 256; off <<= 1) {
    uint32_t x = (t >= off) ? lds[t - off] : 0u; __syncthreads();
    lds[t] += x; __syncthreads();
  }
  uint32_t run = lds[t] - sum;
  #pragma unroll
  for (int k = 0; k < 7; ++k) { int idx = t * 7 + k; if (idx < nb) blockSums[idx] = run; run += local[k]; }
  if (t == 255) totals[0] = run;
}

// ---- scan step 3: per-word (bits, exclusive-prefix) pairs ----
__global__ __launch_bounds__(256) void scan3(const uint32_t* __restrict__ bitmap,
                                             const uint32_t* __restrict__ blockSums,
                                             uint2* __restrict__ pairs) {
  __shared__ uint32_t lds[256];
  int t = threadIdx.x;
  int base = blockIdx.x * 1024 + t * 4;
  uint32_t b[4]; uint32_t c[4]; uint32_t sum = 0;
  if (base + 4 <= WTOT) {
    uint4 w = *reinterpret_cast<const uint4*>(bitmap + base);
    b[0] = w.x; b[1] = w.y; b[2] = w.z; b[3] = w.w;
  } else {
    #pragma unroll
    for (int k = 0; k < 4; ++k) b[k] = (base + k < WTOT) ? bitmap[base + k] : 0u;
  }
  #pragma unroll
  for (int k = 0; k < 4; ++k) { c[k] = __popc(b[k]); sum += c[k]; }
  lds[t] = sum; __syncthreads();
  for (int off = 1; off < 256; off <<= 1) {
    uint32_t x = (t >= off) ? lds[t - off] : 0u; __syncthreads();
    lds[t] += x; __syncthreads();
  }
  uint32_t excl = lds[t] - sum + blockSums[blockIdx.x];
  #pragma unroll
  for (int k = 0; k < 4; ++k) {
    if (base + k < WTOT) pairs[base + k] = make_uint2(b[k], excl);
    excl += c[k];
  }
}

// ---- pass C: per point -> inv (rank); single 8B gather per scale ----
__global__ __launch_bounds__(256) void pass_inv(int n, const uint2* __restrict__ pairs,
                                                const int* __restrict__ keys,
                                                int* __restrict__ out) {
  int i = blockIdx.x * 256 + threadIdx.x;
  if (i >= n) return;
  int key[3] = { keys[i], keys[n + i], keys[2 * n + i] };
  constexpr int RW[3] = {RW0, RW1, RW2};
  #pragma unroll
  for (int s = 0; s < 3; ++s) {
    uint2 pr = pairs[RW[s] + (key[s] >> 5)];
    uint32_t base = pr.y - ((s == 0) ? 0u : pairs[RW[s]].y);
    int rank = (int)(base + __popc(pr.x & ((1u << (key[s] & 31)) - 1u)));
    out[s * STRIDE_OUT + OFF_INV + i] = rank;
  }
}

// ---- pass D: per bitmap word -> coors rows in rank order ----
template <int S>
__global__ __launch_bounds__(256) void pass_coors(const uint2* __restrict__ pairs,
                                                  int* __restrict__ out) {
  constexpr int RW[3] = {RW0, RW1, RW2};
  constexpr int NW[3] = {R2W, R4W, R1W};
  constexpr int D0[3] = {240, 120, 480};
  constexpr int D1[3] = {180,  90, 360};
  constexpr int D2[3] = { 16,   8,  32};
  int wi = blockIdx.x * 256 + threadIdx.x;
  if (wi >= NW[S]) return;
  uint2 pr = pairs[RW[S] + wi];
  uint32_t bits = pr.x;
  if (!bits) return;
  uint32_t rank = pr.y - ((S == 0) ? 0u : pairs[RW[S]].y);
  int keybase = wi * 32;
  int* coors = out + S * STRIDE_OUT + OFF_COORS;
  while (bits) {
    int j = __builtin_ctz(bits);
    bits &= bits - 1;
    int key = keybase + j;
    int gz = key & (D2[S] - 1);
    int r  = key / D2[S];
    int q  = r / D1[S];
    int gy = r - q * D1[S];
    int bq = q / D0[S];
    int gx = q - bq * D0[S];
    *reinterpret_cast<int4*>(coors + (size_t)rank * 4) = make_int4(bq, gz, gy, gx);
    ++rank;
  }
}

// ---- pass E: zero coors tail (dense, one dword/thread), write num ----
__global__ __launch_bounds__(256) void pass_tail(const uint2* __restrict__ pairs,
                                                 const uint32_t* __restrict__ totals,
                                                 int* __restrict__ out, int n) {
  int s = blockIdx.y;
  uint32_t lo = (s == 0) ? 0u : pairs[(s == 1) ? RW1 : RW2].y;
  uint32_t hi = (s == 0) ? pairs[RW1].y : (s == 1) ? pairs[RW2].y : totals[0];
  uint32_t num = hi - lo;
  int i = blockIdx.x * 256 + threadIdx.x;
  if (i == 0) out[s * STRIDE_OUT + OFF_NUM] = (int)num;
  if (i >= 4 * (int)num && i < 4 * n) out[s * STRIDE_OUT + OFF_COORS + i] = 0;
}

extern "C" void kernel_launch(void* const* d_in, const int* in_sizes, int n_in,
                              void* d_out, int out_size, void* d_ws, size_t ws_size,
                              hipStream_t stream) {
  const float4* pts   = (const float4*)d_in[0];
  const int*    batch = (const int*)d_in[1];
  int n = in_sizes[1];  // 2,000,000
  int* out = (int*)d_out;

  // Workspace: rep2s | rep4s | rep1s | bitmap | pairs | blockSums | totals | keys
  // (all hist buffers fully overwritten by plain stores -> NO memset anywhere)
  // J1 ladder keeps us inside ws_size deterministically (graph-safe).
  size_t base_words = (size_t)J2 * R2W + (size_t)J2 * R4W + (size_t)WTOT +
                      2 * (size_t)WTOT + NB1 + 16 + (size_t)3 * n;
  int j1 = 4;
  while (j1 > 1 && (base_words + (size_t)j1 * R1W) * 4 > ws_size) j1 >>= 1;

  uint32_t* rep2s     = (uint32_t*)d_ws;
  uint32_t* rep4s     = rep2s + (size_t)J2 * R2W;
  uint32_t* rep1s     = rep4s + (size_t)J2 * R4W;
  uint32_t* bitmap    = rep1s + (size_t)j1 * R1W;
  uint2*    pairs     = (uint2*)(bitmap + WTOT);
  uint32_t* blockSums = (uint32_t*)(pairs + WTOT);
  uint32_t* totals    = blockSums + NB1;
  int*      keys      = (int*)(totals + 16);

  int nblk = (n + 255) / 256;
  pass_points<<<nblk, 256, 0, stream>>>(pts, batch, n, keys, out);
  hist24<<<64, 1024, 0, stream>>>(batch, keys, n, rep2s, rep4s);
  hist1<<<64 * j1, 1024, 0, stream>>>(batch, keys, n, rep1s, j1);
  merge_region<<<(R2W / 4 + 255) / 256, 256, 0, stream>>>(rep2s, bitmap + RW0, R2W, J2);
  merge_region<<<(R4W / 4 + 255) / 256, 256, 0, stream>>>(rep4s, bitmap + RW1, R4W, J2);
  merge_region<<<(R1W / 4 + 255) / 256, 256, 0, stream>>>(rep1s, bitmap + RW2, R1W, j1);
  scan1<<<NB1, 256, 0, stream>>>(bitmap, blockSums);
  scan2<<<1, 256, 0, stream>>>(blockSums, totals, NB1);
  scan3<<<NB1, 256, 0, stream>>>(bitmap, blockSums, pairs);
  pass_inv<<<nblk, 256, 0, stream>>>(n, pairs, keys, out);
  pass_coors<0><<<(R2W + 255) / 256, 256, 0, stream>>>(pairs, out);
  pass_coors<1><<<(R4W + 255) / 256, 256, 0, stream>>>(pairs, out);
  pass_coors<2><<<(R1W + 255) / 256, 256, 0, stream>>>(pairs, out);
  dim3 gtail((unsigned)((4 * n + 255) / 256), 3);
  pass_tail<<<gtail, 256, 0, stream>>>(pairs, totals, out, n);
}

// Round 6
// 373.252 us; speedup vs baseline: 3.9000x; 1.1146x over previous
//
#include <hip/hip_runtime.h>
#include <cstdint>

#define DI __device__ __forceinline__

// ---- problem constants (N=2e6, spatial=[480,360,32], scales=[2,4,1], 8 batches, sorted) ----
constexpr int NPTS       = 2000000;
constexpr int STRIDE_OUT = 18000001;   // per-scale output stride in int32 elements
constexpr int OFF_INV    = 8000000;
constexpr int OFF_COORS  = 10000000;
constexpr int OFF_NUM    = 18000000;

// scale=2: 240x180x16 ; scale=4: 120x90x8 ; scale=1: 480x360x32
constexpr int R2W  = 172800;    // words; per-batch slice 21600 w (86.4 KB LDS)
constexpr int R4W  = 21600;     // words; per-batch slice 2700 w
constexpr int R1W  = 1382400;   // words; per-(batch,rho/8) slice 21600 w
constexpr int RW0  = 0;
constexpr int RW1  = R2W;
constexpr int RW2  = R2W + R4W;
constexpr int WTOT = R2W + R4W + R1W;       // 1576800
constexpr int NB1  = (WTOT + 1023) / 1024;  // scan blocks (1540)
constexpr int J2   = 8;                     // copies for scale-2/4 hist

// epilogue block partition
constexpr int NBLK_INV   = (NPTS + 255) / 256;        // 7813
constexpr int NBLK_COORS = (WTOT + 255) / 256;        // 6160
constexpr int NBLK_TAIL  = (3 * NPTS + 255) / 256;    // 23438

// ---- strict (non-contractible) f32 ops: bit-match XLA's mul,mul,add,sqrt ----
DI float fmul_s(float a, float b){ float r; asm("v_mul_f32 %0, %1, %2" : "=v"(r) : "v"(a), "v"(b)); return r; }
DI float fadd_s(float a, float b){ float r; asm("v_add_f32 %0, %1, %2" : "=v"(r) : "v"(a), "v"(b)); return r; }

DI void compute_keys(float x, float y, float z, int b, int (&key)[3], int (&g0)[3], int (&g1)[3], int (&g2)[3]) {
  const float PI_F     = 3.14159265358979323846f;
  const float TWO_PI_F = 6.28318530717958647692f;
  float rho = sqrtf(fadd_s(fmul_s(x, x), fmul_s(y, y)));
  float phi = atan2f(y, x);
  float tr = (fminf(fmaxf(rho, 0.0f), 50.0f) - 0.0f) / 50.0f;
  float tp = (fminf(fmaxf(phi, -PI_F), PI_F) + PI_F) / TWO_PI_F;
  float tz = (fminf(fmaxf(z, -4.0f), 2.0f) + 4.0f) / 6.0f;
  constexpr float C0[3] = {239.f, 119.f, 479.f};
  constexpr float C1[3] = {179.f,  89.f, 359.f};
  constexpr float C2[3] = { 15.f,   7.f,  31.f};
  constexpr int   D0[3] = {240, 120, 480};
  constexpr int   D1[3] = {180,  90, 360};
  constexpr int   D2[3] = { 16,   8,  32};
  #pragma unroll
  for (int s = 0; s < 3; ++s) {
    int a0 = (int)floorf(tr * C0[s]);
    int a1 = (int)floorf(tp * C1[s]);
    int a2 = (int)floorf(tz * C2[s]);
    g0[s] = a0; g1[s] = a1; g2[s] = a2;
    key[s] = ((b * D0[s] + a0) * D1[s] + a1) * D2[s] + a2;
  }
}

DI int lower_bound(const int* __restrict__ a, int n, int v) {
  int lo = 0, hi = n;
  while (lo < hi) { int m = (lo + hi) >> 1; if (a[m] < v) lo = m + 1; else hi = m; }
  return lo;
}

// ---- pass 1: per point -> bxyz + keys. zero atomics. ----
__global__ __launch_bounds__(256) void pass_points(const float4* __restrict__ pts,
                                                   const int* __restrict__ batch, int n,
                                                   int* __restrict__ keys,
                                                   int* __restrict__ out) {
  int i = blockIdx.x * 256 + threadIdx.x;
  if (i >= n) return;
  float4 p = pts[i];
  int b = batch[i];
  int key[3], g0[3], g1[3], g2[3];
  compute_keys(p.x, p.y, p.z, b, key, g0, g1, g2);
  #pragma unroll
  for (int s = 0; s < 3; ++s)
    *reinterpret_cast<int4*>(out + s * STRIDE_OUT + i * 4) = make_int4(b, g0[s], g1[s], g2[s]);
  keys[i] = key[0]; keys[n + i] = key[1]; keys[2 * n + i] = key[2];
}

// ---- pass 2: fused LDS histograms. blocks [0,64): scale-2+4; [64,64+64*j1): scale-1 ----
// All rep words are plain-stored (zeros included) -> no memset anywhere.
__global__ __launch_bounds__(1024) void hist_all(const int* __restrict__ batch,
                                                 const int* __restrict__ keys, int n,
                                                 uint32_t* __restrict__ rep2s,
                                                 uint32_t* __restrict__ rep4s,
                                                 uint32_t* __restrict__ rep1s, int j1) {
  alignas(16) __shared__ uint32_t bmA[21600];   // scale-2 slice / scale-1 slice
  alignas(16) __shared__ uint32_t bmB[2700];    // scale-4 slice (hist24 role only)
  int t = threadIdx.x;
  if ((int)blockIdx.x < 64) {
    int bv = blockIdx.x >> 3, j = blockIdx.x & 7;
    for (int w = t * 4; w < 21600; w += 4096) *reinterpret_cast<uint4*>(bmA + w) = make_uint4(0,0,0,0);
    for (int w = t; w < 2700; w += 1024) bmB[w] = 0;
    __syncthreads();
    int lo = lower_bound(batch, n, bv);
    int hi = lower_bound(batch, n, bv + 1);
    int sz = hi - lo;
    int s = lo + (int)((long long)sz * j / J2);
    int e = lo + (int)((long long)sz * (j + 1) / J2);
    const int* k0 = keys;
    const int* k1 = keys + n;
    for (int i = s + t; i < e; i += 1024) {
      int ink2 = k0[i] - bv * 691200;   // 240*180*16 bits/batch
      int ink4 = k1[i] - bv * 86400;    // 120*90*8 bits/batch
      atomicOr(&bmA[ink2 >> 5], 1u << (ink2 & 31));
      atomicOr(&bmB[ink4 >> 5], 1u << (ink4 & 31));
    }
    __syncthreads();
    uint32_t* d2 = rep2s + (size_t)j * R2W + bv * 21600;
    uint32_t* d4 = rep4s + (size_t)j * R4W + bv * 2700;
    for (int w = t * 4; w < 21600; w += 4096) *reinterpret_cast<uint4*>(d2 + w) = *reinterpret_cast<uint4*>(bmA + w);
    for (int w = t * 4; w < 2700; w += 4096) *reinterpret_cast<uint4*>(d4 + w) = *reinterpret_cast<uint4*>(bmB + w);
  } else {
    int idx = blockIdx.x - 64;
    int j = idx >> 6;
    int slice = idx & 63;               // bv*8 + r
    int bv = slice >> 3, r = slice & 7;
    for (int w = t * 4; w < 21600; w += 4096) *reinterpret_cast<uint4*>(bmA + w) = make_uint4(0,0,0,0);
    __syncthreads();
    int lo = lower_bound(batch, n, bv);
    int hi = lower_bound(batch, n, bv + 1);
    int sz = hi - lo;
    int s = lo + (int)((long long)sz * j / j1);
    int e = lo + (int)((long long)sz * (j + 1) / j1);
    const int* k2 = keys + 2 * n;
    int base = bv * 5529600 + r * 691200;
    for (int i = s + t; i < e; i += 1024) {
      int rel = k2[i] - base;           // in [0,691200) iff in our rho range
      if ((unsigned)rel < 691200u) atomicOr(&bmA[rel >> 5], 1u << (rel & 31));
    }
    __syncthreads();
    uint32_t* d = rep1s + (size_t)j * R1W + (size_t)slice * 21600;
    for (int w = t * 4; w < 21600; w += 4096) *reinterpret_cast<uint4*>(d + w) = *reinterpret_cast<uint4*>(bmA + w);
  }
}

// ---- merge copies for a 4-word group at word index `base` ----
DI uint4 merged_words(int base, const uint32_t* __restrict__ rep2s,
                      const uint32_t* __restrict__ rep4s,
                      const uint32_t* __restrict__ rep1s, int j1) {
  uint4 acc = make_uint4(0, 0, 0, 0);
  if (base < RW1) {
    #pragma unroll
    for (int c = 0; c < J2; ++c) {
      uint4 w = *reinterpret_cast<const uint4*>(rep2s + (size_t)c * R2W + base);
      acc.x |= w.x; acc.y |= w.y; acc.z |= w.z; acc.w |= w.w;
    }
  } else if (base < RW2) {
    int l = base - RW1;
    #pragma unroll
    for (int c = 0; c < J2; ++c) {
      uint4 w = *reinterpret_cast<const uint4*>(rep4s + (size_t)c * R4W + l);
      acc.x |= w.x; acc.y |= w.y; acc.z |= w.z; acc.w |= w.w;
    }
  } else {
    int l = base - RW2;
    for (int c = 0; c < j1; ++c) {
      uint4 w = *reinterpret_cast<const uint4*>(rep1s + (size_t)c * R1W + l);
      acc.x |= w.x; acc.y |= w.y; acc.z |= w.z; acc.w |= w.w;
    }
  }
  return acc;
}

// ---- pass 3: scanA — merge on the fly, write bits[] + per-block popcount sums ----
__global__ __launch_bounds__(256) void scanA(const uint32_t* __restrict__ rep2s,
                                             const uint32_t* __restrict__ rep4s,
                                             const uint32_t* __restrict__ rep1s, int j1,
                                             uint32_t* __restrict__ bits,
                                             uint32_t* __restrict__ blockSums) {
  __shared__ uint32_t lds[256];
  int t = threadIdx.x;
  int base = blockIdx.x * 1024 + t * 4;
  uint32_t s = 0;
  if (base < WTOT) {       // WTOT%4==0: group fully in or out; regions 4-aligned
    uint4 m = merged_words(base, rep2s, rep4s, rep1s, j1);
    *reinterpret_cast<uint4*>(bits + base) = m;
    s = __popc(m.x) + __popc(m.y) + __popc(m.z) + __popc(m.w);
  }
  lds[t] = s; __syncthreads();
  for (int off = 128; off > 0; off >>= 1) { if (t < off) lds[t] += lds[t + off]; __syncthreads(); }
  if (t == 0) blockSums[blockIdx.x] = lds[0];
}

// ---- pass 4: scanB — exclusive scan of block sums; totals[0] = grand total ----
__global__ __launch_bounds__(256) void scanB(uint32_t* __restrict__ blockSums,
                                             uint32_t* __restrict__ totals, int nb) {
  __shared__ uint32_t lds[256];
  int t = threadIdx.x;
  uint32_t local[7]; uint32_t sum = 0;
  #pragma unroll
  for (int k = 0; k < 7; ++k) { int idx = t * 7 + k; uint32_t v = (idx < nb) ? blockSums[idx] : 0u; local[k] = v; sum += v; }
  lds[t] = sum; __syncthreads();
  for (int off = 1; off < 256; off <<= 1) {
    uint32_t x = (t >= off) ? lds[t - off] : 0u; __syncthreads();
    lds[t] += x; __syncthreads();
  }
  uint32_t run = lds[t] - sum;
  #pragma unroll
  for (int k = 0; k < 7; ++k) { int idx = t * 7 + k; if (idx < nb) blockSums[idx] = run; run += local[k]; }
  if (t == 255) totals[0] = run;
}

// ---- pass 5: scanC — per-word (bits, exclusive-prefix) pairs ----
__global__ __launch_bounds__(256) void scanC(const uint32_t* __restrict__ bits,
                                             const uint32_t* __restrict__ blockSums,
                                             uint2* __restrict__ pairs) {
  __shared__ uint32_t lds[256];
  int t = threadIdx.x;
  int base = blockIdx.x * 1024 + t * 4;
  uint32_t b[4] = {0,0,0,0}; uint32_t c[4]; uint32_t sum = 0;
  if (base < WTOT) {
    uint4 w = *reinterpret_cast<const uint4*>(bits + base);
    b[0] = w.x; b[1] = w.y; b[2] = w.z; b[3] = w.w;
  }
  #pragma unroll
  for (int k = 0; k < 4; ++k) { c[k] = __popc(b[k]); sum += c[k]; }
  lds[t] = sum; __syncthreads();
  for (int off = 1; off < 256; off <<= 1) {
    uint32_t x = (t >= off) ? lds[t - off] : 0u; __syncthreads();
    lds[t] += x; __syncthreads();
  }
  uint32_t excl = lds[t] - sum + blockSums[blockIdx.x];
  if (base < WTOT) {
    #pragma unroll
    for (int k = 0; k < 4; ++k) { pairs[base + k] = make_uint2(b[k], excl); excl += c[k]; }
  }
}

// ---- coors word decode (compile-time scale constants -> magic-mul division) ----
template <int S>
DI void coors_word(int wi_local, uint32_t bits, uint32_t rank, int* __restrict__ coors) {
  constexpr int D0[3] = {240, 120, 480};
  constexpr int D1[3] = {180,  90, 360};
  constexpr int D2[3] = { 16,   8,  32};
  int keybase = wi_local * 32;
  while (bits) {
    int j = __builtin_ctz(bits);
    bits &= bits - 1;
    int key = keybase + j;
    int gz = key & (D2[S] - 1);
    int r  = key / D2[S];
    int q  = r / D1[S];
    int gy = r - q * D1[S];
    int bq = q / D0[S];
    int gx = q - bq * D0[S];
    *reinterpret_cast<int4*>(coors + (size_t)rank * 4) = make_int4(bq, gz, gy, gx);
    ++rank;
  }
}

// ---- pass 6: fused epilogue — inv | coors | tail+num, partitioned by blockIdx ----
// All three roles depend only on (pairs, blockSums-scanned, totals, keys) and
// write DISJOINT d_out regions -> race-free in one launch; HW overlaps the
// latency-bound inv gathers with the store-bound coors/tail streams.
__global__ __launch_bounds__(256) void epilogue(int n, const uint2* __restrict__ pairs,
                                                const uint32_t* __restrict__ totals,
                                                const int* __restrict__ keys,
                                                int* __restrict__ out) {
  int b = blockIdx.x;
  int t = threadIdx.x;
  if (b < NBLK_INV) {
    // ---- inv: one point per thread, one 8B gather per scale ----
    int i = b * 256 + t;
    if (i >= n) return;
    int key[3] = { keys[i], keys[n + i], keys[2 * n + i] };
    constexpr int RW[3] = {RW0, RW1, RW2};
    #pragma unroll
    for (int s = 0; s < 3; ++s) {
      uint2 pr = pairs[RW[s] + (key[s] >> 5)];
      uint32_t base = pr.y - ((s == 0) ? 0u : pairs[RW[s]].y);
      int rank = (int)(base + __popc(pr.x & ((1u << (key[s] & 31)) - 1u)));
      out[s * STRIDE_OUT + OFF_INV + i] = rank;
    }
  } else if (b < NBLK_INV + NBLK_COORS) {
    // ---- coors: one bitmap word per thread, rows written in rank order ----
    int wi = (b - NBLK_INV) * 256 + t;
    if (wi >= WTOT) return;
    uint2 pr = pairs[wi];
    if (!pr.x) return;
    if (wi < RW1) {
      coors_word<0>(wi, pr.x, pr.y, out + 0 * STRIDE_OUT + OFF_COORS);
    } else if (wi < RW2) {
      coors_word<1>(wi - RW1, pr.x, pr.y - pairs[RW1].y, out + 1 * STRIDE_OUT + OFF_COORS);
    } else {
      coors_word<2>(wi - RW2, pr.x, pr.y - pairs[RW2].y, out + 2 * STRIDE_OUT + OFF_COORS);
    }
  } else {
    // ---- tail: one int4 row per thread; zero rows [num, n); write num ----
    int idx = (b - NBLK_INV - NBLK_COORS) * 256 + t;   // row index in [0, 3n)
    int s = 0, i = idx;
    if (i >= 2 * n)      { s = 2; i -= 2 * n; }
    else if (i >= n)     { s = 1; i -= n; }
    if (idx >= 3 * n) return;
    uint32_t lo = (s == 0) ? 0u : pairs[(s == 1) ? RW1 : RW2].y;
    uint32_t hi = (s == 0) ? pairs[RW1].y : (s == 1) ? pairs[RW2].y : totals[0];
    uint32_t num = hi - lo;
    if (i == 0) out[s * STRIDE_OUT + OFF_NUM] = (int)num;
    if ((uint32_t)i >= num)
      *reinterpret_cast<int4*>(out + s * STRIDE_OUT + OFF_COORS + (size_t)i * 4) = make_int4(0, 0, 0, 0);
  }
}

extern "C" void kernel_launch(void* const* d_in, const int* in_sizes, int n_in,
                              void* d_out, int out_size, void* d_ws, size_t ws_size,
                              hipStream_t stream) {
  const float4* pts   = (const float4*)d_in[0];
  const int*    batch = (const int*)d_in[1];
  int n = in_sizes[1];  // 2,000,000
  int* out = (int*)d_out;

  // ws: rep2s | rep4s | rep1s | bits | pairs | blockSums | totals | keys  (no memsets)
  size_t base_words = (size_t)J2 * R2W + (size_t)J2 * R4W + (size_t)WTOT +
                      2 * (size_t)WTOT + NB1 + 16 + (size_t)3 * n;
  int j1 = 4;
  while (j1 > 1 && (base_words + (size_t)j1 * R1W) * 4 > ws_size) j1 >>= 1;

  uint32_t* rep2s     = (uint32_t*)d_ws;
  uint32_t* rep4s     = rep2s + (size_t)J2 * R2W;
  uint32_t* rep1s     = rep4s + (size_t)J2 * R4W;
  uint32_t* bits      = rep1s + (size_t)j1 * R1W;
  uint2*    pairs     = (uint2*)(bits + WTOT);
  uint32_t* blockSums = (uint32_t*)(pairs + WTOT);
  uint32_t* totals    = blockSums + NB1;
  int*      keys      = (int*)(totals + 16);

  int nblk = (n + 255) / 256;
  pass_points<<<nblk, 256, 0, stream>>>(pts, batch, n, keys, out);
  hist_all<<<64 + 64 * j1, 1024, 0, stream>>>(batch, keys, n, rep2s, rep4s, rep1s, j1);
  scanA<<<NB1, 256, 0, stream>>>(rep2s, rep4s, rep1s, j1, bits, blockSums);
  scanB<<<1, 256, 0, stream>>>(blockSums, totals, NB1);
  scanC<<<NB1, 256, 0, stream>>>(bits, blockSums, pairs);
  epilogue<<<NBLK_INV + NBLK_COORS + NBLK_TAIL, 256, 0, stream>>>(n, pairs, totals, keys, out);
}

// Round 7
// 345.551 us; speedup vs baseline: 4.2126x; 1.0802x over previous
//
#include <hip/hip_runtime.h>
#include <cstdint>

#define DI __device__ __forceinline__

// ---- problem constants (N=2e6, spatial=[480,360,32], scales=[2,4,1], 8 batches, sorted) ----
constexpr int NPTS       = 2000000;
constexpr int STRIDE_OUT = 18000001;   // per-scale output stride in int32 elements
constexpr int OFF_INV    = 8000000;
constexpr int OFF_COORS  = 10000000;
constexpr int OFF_NUM    = 18000000;

// scale=2: 240x180x16 ; scale=4: 120x90x8 ; scale=1: 480x360x32
constexpr int R2W  = 172800;    // words; per-batch slice 21600 w (86.4 KB LDS)
constexpr int R4W  = 21600;     // words; per-batch slice 2700 w
constexpr int R1W  = 1382400;   // words; per-(batch,rho/6) slice 28800 w (115.2 KB LDS)
constexpr int RW0  = 0;
constexpr int RW1  = R2W;
constexpr int RW2  = R2W + R4W;
constexpr int WTOT = R2W + R4W + R1W;       // 1576800
constexpr int NB1  = (WTOT + 1023) / 1024;  // scan blocks (1540)
constexpr int J2   = 8;                     // copies/chunks for scale-2/4 hist
constexpr int P1   = 6;                     // rho partitions for scale-1 (6*28800=172800 w/batch)
constexpr int J1   = 4;                     // copies/chunks for scale-1
constexpr int S1W  = 28800;                 // words per scale-1 slice
constexpr int S1BITS = S1W * 32;            // 921600 bits per slice

// epilogue block partition
constexpr int NBLK_INV   = (NPTS + 255) / 256;        // 7813
constexpr int NBLK_COORS = (WTOT + 255) / 256;        // 6160
constexpr int NBLK_TAIL  = (3 * NPTS + 255) / 256;    // 23438

// ---- strict (non-contractible) f32 ops: bit-match XLA's mul,mul,add,sqrt ----
DI float fmul_s(float a, float b){ float r; asm("v_mul_f32 %0, %1, %2" : "=v"(r) : "v"(a), "v"(b)); return r; }
DI float fadd_s(float a, float b){ float r; asm("v_add_f32 %0, %1, %2" : "=v"(r) : "v"(a), "v"(b)); return r; }

DI void compute_keys(float x, float y, float z, int b, int (&key)[3]) {
  const float PI_F     = 3.14159265358979323846f;
  const float TWO_PI_F = 6.28318530717958647692f;
  float rho = sqrtf(fadd_s(fmul_s(x, x), fmul_s(y, y)));
  float phi = atan2f(y, x);
  float tr = (fminf(fmaxf(rho, 0.0f), 50.0f) - 0.0f) / 50.0f;
  float tp = (fminf(fmaxf(phi, -PI_F), PI_F) + PI_F) / TWO_PI_F;
  float tz = (fminf(fmaxf(z, -4.0f), 2.0f) + 4.0f) / 6.0f;
  constexpr float C0[3] = {239.f, 119.f, 479.f};
  constexpr float C1[3] = {179.f,  89.f, 359.f};
  constexpr float C2[3] = { 15.f,   7.f,  31.f};
  constexpr int   D0[3] = {240, 120, 480};
  constexpr int   D1[3] = {180,  90, 360};
  constexpr int   D2[3] = { 16,   8,  32};
  #pragma unroll
  for (int s = 0; s < 3; ++s) {
    int a0 = (int)floorf(tr * C0[s]);
    int a1 = (int)floorf(tp * C1[s]);
    int a2 = (int)floorf(tz * C2[s]);
    key[s] = ((b * D0[s] + a0) * D1[s] + a1) * D2[s] + a2;
  }
}

DI int lower_bound(const int* __restrict__ a, int n, int v) {
  int lo = 0, hi = n;
  while (lo < hi) { int m = (lo + hi) >> 1; if (a[m] < v) lo = m + 1; else hi = m; }
  return lo;
}

// ---- pass 1: per point -> 3 key planes. (bxyz moved to epilogue: exact int decode) ----
__global__ __launch_bounds__(256) void pass_keys(const float4* __restrict__ pts,
                                                 const int* __restrict__ batch, int n,
                                                 int* __restrict__ keys) {
  int i = blockIdx.x * 256 + threadIdx.x;
  if (i >= n) return;
  float4 p = pts[i];
  int key[3];
  compute_keys(p.x, p.y, p.z, batch[i], key);
  keys[i] = key[0]; keys[n + i] = key[1]; keys[2 * n + i] = key[2];
}

// ---- pass 2: fused LDS histograms, EXACTLY 256 blocks (one occupancy wave) ----
// blocks [0,64): (bv,j) scale-2+4 slices; [64,256): (j,bv,r) scale-1 slices.
// Every rep word is plain-stored (zeros included) -> no memset anywhere.
__global__ __launch_bounds__(1024) void hist_all(const int* __restrict__ batch,
                                                 const int* __restrict__ keys, int n,
                                                 uint32_t* __restrict__ rep2s,
                                                 uint32_t* __restrict__ rep4s,
                                                 uint32_t* __restrict__ rep1s) {
  alignas(16) __shared__ uint32_t bmA[S1W];     // scale-1 slice / scale-2 slice (first 21600)
  alignas(16) __shared__ uint32_t bmB[2700];    // scale-4 slice (2/4 role only)
  int t = threadIdx.x;
  if ((int)blockIdx.x < 64) {
    int bv = blockIdx.x >> 3, j = blockIdx.x & 7;
    for (int w = t * 4; w < 21600; w += 4096) *reinterpret_cast<uint4*>(bmA + w) = make_uint4(0,0,0,0);
    for (int w = t; w < 2700; w += 1024) bmB[w] = 0;
    __syncthreads();
    int lo = lower_bound(batch, n, bv);
    int hi = lower_bound(batch, n, bv + 1);
    int sz = hi - lo;
    int s = lo + (int)((long long)sz * j / J2);
    int e = lo + (int)((long long)sz * (j + 1) / J2);
    const int* k0 = keys;
    const int* k1 = keys + n;
    for (int i = s + t; i < e; i += 1024) {
      int ink2 = k0[i] - bv * 691200;   // 240*180*16 bits/batch
      int ink4 = k1[i] - bv * 86400;    // 120*90*8 bits/batch
      atomicOr(&bmA[ink2 >> 5], 1u << (ink2 & 31));
      atomicOr(&bmB[ink4 >> 5], 1u << (ink4 & 31));
    }
    __syncthreads();
    uint32_t* d2 = rep2s + (size_t)j * R2W + bv * 21600;
    uint32_t* d4 = rep4s + (size_t)j * R4W + bv * 2700;
    for (int w = t * 4; w < 21600; w += 4096) *reinterpret_cast<uint4*>(d2 + w) = *reinterpret_cast<uint4*>(bmA + w);
    for (int w = t * 4; w < 2700; w += 4096) *reinterpret_cast<uint4*>(d4 + w) = *reinterpret_cast<uint4*>(bmB + w);
  } else {
    int idx = blockIdx.x - 64;          // [0, 192)
    int j = idx / 48;                   // chunk
    int slice = idx - j * 48;           // bv*6 + r
    int bv = slice / 6, r = slice - bv * 6;
    for (int w = t * 4; w < S1W; w += 4096) *reinterpret_cast<uint4*>(bmA + w) = make_uint4(0,0,0,0);
    __syncthreads();
    int lo = lower_bound(batch, n, bv);
    int hi = lower_bound(batch, n, bv + 1);
    int sz = hi - lo;
    int s = lo + (int)((long long)sz * j / J1);
    int e = lo + (int)((long long)sz * (j + 1) / J1);
    const int* k2 = keys + 2 * n;
    int base = bv * 5529600 + r * S1BITS;
    for (int i = s + t; i < e; i += 1024) {
      int rel = k2[i] - base;           // in [0, S1BITS) iff in our rho range
      if ((unsigned)rel < (unsigned)S1BITS) atomicOr(&bmA[rel >> 5], 1u << (rel & 31));
    }
    __syncthreads();
    uint32_t* d = rep1s + (size_t)j * R1W + (size_t)slice * S1W;
    for (int w = t * 4; w < S1W; w += 4096) *reinterpret_cast<uint4*>(d + w) = *reinterpret_cast<uint4*>(bmA + w);
  }
}

// ---- merge copies for a 4-word group at word index `base` ----
DI uint4 merged_words(int base, const uint32_t* __restrict__ rep2s,
                      const uint32_t* __restrict__ rep4s,
                      const uint32_t* __restrict__ rep1s) {
  uint4 acc = make_uint4(0, 0, 0, 0);
  if (base < RW1) {
    #pragma unroll
    for (int c = 0; c < J2; ++c) {
      uint4 w = *reinterpret_cast<const uint4*>(rep2s + (size_t)c * R2W + base);
      acc.x |= w.x; acc.y |= w.y; acc.z |= w.z; acc.w |= w.w;
    }
  } else if (base < RW2) {
    int l = base - RW1;
    #pragma unroll
    for (int c = 0; c < J2; ++c) {
      uint4 w = *reinterpret_cast<const uint4*>(rep4s + (size_t)c * R4W + l);
      acc.x |= w.x; acc.y |= w.y; acc.z |= w.z; acc.w |= w.w;
    }
  } else {
    int l = base - RW2;
    #pragma unroll
    for (int c = 0; c < J1; ++c) {
      uint4 w = *reinterpret_cast<const uint4*>(rep1s + (size_t)c * R1W + l);
      acc.x |= w.x; acc.y |= w.y; acc.z |= w.z; acc.w |= w.w;
    }
  }
  return acc;
}

// ---- pass 3: scanA — merge on the fly, write bits[] + per-block popcount sums ----
__global__ __launch_bounds__(256) void scanA(const uint32_t* __restrict__ rep2s,
                                             const uint32_t* __restrict__ rep4s,
                                             const uint32_t* __restrict__ rep1s,
                                             uint32_t* __restrict__ bits,
                                             uint32_t* __restrict__ blockSums) {
  __shared__ uint32_t lds[256];
  int t = threadIdx.x;
  int base = blockIdx.x * 1024 + t * 4;
  uint32_t s = 0;
  if (base < WTOT) {       // WTOT%4==0; regions 4-aligned
    uint4 m = merged_words(base, rep2s, rep4s, rep1s);
    *reinterpret_cast<uint4*>(bits + base) = m;
    s = __popc(m.x) + __popc(m.y) + __popc(m.z) + __popc(m.w);
  }
  lds[t] = s; __syncthreads();
  for (int off = 128; off > 0; off >>= 1) { if (t < off) lds[t] += lds[t + off]; __syncthreads(); }
  if (t == 0) blockSums[blockIdx.x] = lds[0];
}

// ---- pass 4: scanC — per-word (bits, excl-prefix) pairs; each block sums its own base
// from blockSums[0..b) (L2-broadcast, <=6KB) -> no separate scanB launch. ----
__global__ __launch_bounds__(256) void scanC(const uint32_t* __restrict__ bits,
                                             const uint32_t* __restrict__ blockSums,
                                             uint2* __restrict__ pairs) {
  __shared__ uint32_t lds[256];
  int t = threadIdx.x;
  // block base = sum of blockSums[0 .. blockIdx.x)
  uint32_t bs = 0;
  for (int k = t; k < (int)blockIdx.x; k += 256) bs += blockSums[k];
  lds[t] = bs; __syncthreads();
  for (int off = 128; off > 0; off >>= 1) { if (t < off) lds[t] += lds[t + off]; __syncthreads(); }
  uint32_t blockBase = lds[0];
  __syncthreads();
  int base = blockIdx.x * 1024 + t * 4;
  uint32_t b[4] = {0,0,0,0}; uint32_t c[4]; uint32_t sum = 0;
  if (base < WTOT) {
    uint4 w = *reinterpret_cast<const uint4*>(bits + base);
    b[0] = w.x; b[1] = w.y; b[2] = w.z; b[3] = w.w;
  }
  #pragma unroll
  for (int k = 0; k < 4; ++k) { c[k] = __popc(b[k]); sum += c[k]; }
  lds[t] = sum; __syncthreads();
  for (int off = 1; off < 256; off <<= 1) {
    uint32_t x = (t >= off) ? lds[t - off] : 0u; __syncthreads();
    lds[t] += x; __syncthreads();
  }
  uint32_t excl = lds[t] - sum + blockBase;
  if (base < WTOT) {
    #pragma unroll
    for (int k = 0; k < 4; ++k) { pairs[base + k] = make_uint2(b[k], excl); excl += c[k]; }
  }
}

// ---- exact integer key decode (pow2 masks + magic-mul const division) ----
template <int S>
DI int4 decode_key(int key) {   // returns (b, a0, a1, a2)
  constexpr int D0[3] = {240, 120, 480};
  constexpr int D1[3] = {180,  90, 360};
  constexpr int D2[3] = { 16,   8,  32};
  int a2 = key & (D2[S] - 1);
  int r  = key / D2[S];
  int q  = r / D1[S];
  int a1 = r - q * D1[S];
  int b  = q / D0[S];
  int a0 = q - b * D0[S];
  return make_int4(b, a0, a1, a2);
}

template <int S>
DI void coors_word(int wi_local, uint32_t bits, uint32_t rank, int* __restrict__ coors) {
  int keybase = wi_local * 32;
  while (bits) {
    int j = __builtin_ctz(bits);
    bits &= bits - 1;
    int4 d = decode_key<S>(keybase + j);
    *reinterpret_cast<int4*>(coors + (size_t)rank * 4) = make_int4(d.x, d.w, d.z, d.y);  // [b,z,phi,rho]
    ++rank;
  }
}

// ---- pass 5: fused epilogue — (bxyz+inv) | coors | tail+num, partitioned by blockIdx.
// Disjoint d_out regions -> race-free; bxyz store streams overlap inv gather latency. ----
__global__ __launch_bounds__(256) void epilogue(int n, const uint2* __restrict__ pairs,
                                                const int* __restrict__ keys,
                                                int* __restrict__ out) {
  int b = blockIdx.x;
  int t = threadIdx.x;
  if (b < NBLK_INV) {
    // ---- bxyz (decoded from key) + inv (one 8B gather per scale) ----
    int i = b * 256 + t;
    if (i >= n) return;
    int key[3] = { keys[i], keys[n + i], keys[2 * n + i] };
    constexpr int RW[3] = {RW0, RW1, RW2};
    *reinterpret_cast<int4*>(out + 0 * STRIDE_OUT + i * 4) = decode_key<0>(key[0]);
    *reinterpret_cast<int4*>(out + 1 * STRIDE_OUT + i * 4) = decode_key<1>(key[1]);
    *reinterpret_cast<int4*>(out + 2 * STRIDE_OUT + i * 4) = decode_key<2>(key[2]);
    #pragma unroll
    for (int s = 0; s < 3; ++s) {
      uint2 pr = pairs[RW[s] + (key[s] >> 5)];
      uint32_t base = pr.y - ((s == 0) ? 0u : pairs[RW[s]].y);
      int rank = (int)(base + __popc(pr.x & ((1u << (key[s] & 31)) - 1u)));
      out[s * STRIDE_OUT + OFF_INV + i] = rank;
    }
  } else if (b < NBLK_INV + NBLK_COORS) {
    // ---- coors: one bitmap word per thread, rows in rank order ----
    int wi = (b - NBLK_INV) * 256 + t;
    if (wi >= WTOT) return;
    uint2 pr = pairs[wi];
    if (!pr.x) return;
    if (wi < RW1)      coors_word<0>(wi,       pr.x, pr.y,                 out + 0 * STRIDE_OUT + OFF_COORS);
    else if (wi < RW2) coors_word<1>(wi - RW1, pr.x, pr.y - pairs[RW1].y,  out + 1 * STRIDE_OUT + OFF_COORS);
    else               coors_word<2>(wi - RW2, pr.x, pr.y - pairs[RW2].y,  out + 2 * STRIDE_OUT + OFF_COORS);
  } else {
    // ---- tail: one int4 row per thread; zero rows [num, n); write num ----
    int idx = (b - NBLK_INV - NBLK_COORS) * 256 + t;   // row in [0, 3n)
    if (idx >= 3 * n) return;
    int s = 0, i = idx;
    if (i >= 2 * n)  { s = 2; i -= 2 * n; }
    else if (i >= n) { s = 1; i -= n; }
    uint2 last = pairs[WTOT - 1];
    uint32_t total = last.y + (uint32_t)__popc(last.x);
    uint32_t lo = (s == 0) ? 0u : pairs[(s == 1) ? RW1 : RW2].y;
    uint32_t hi = (s == 0) ? pairs[RW1].y : (s == 1) ? pairs[RW2].y : total;
    uint32_t num = hi - lo;
    if (i == 0) out[s * STRIDE_OUT + OFF_NUM] = (int)num;
    if ((uint32_t)i >= num)
      *reinterpret_cast<int4*>(out + s * STRIDE_OUT + OFF_COORS + (size_t)i * 4) = make_int4(0, 0, 0, 0);
  }
}

extern "C" void kernel_launch(void* const* d_in, const int* in_sizes, int n_in,
                              void* d_out, int out_size, void* d_ws, size_t ws_size,
                              hipStream_t stream) {
  const float4* pts   = (const float4*)d_in[0];
  const int*    batch = (const int*)d_in[1];
  int n = in_sizes[1];  // 2,000,000
  int* out = (int*)d_out;

  // ws: rep2s | rep4s | rep1s | bits | pairs | blockSums | keys  (~72 MB, no memsets)
  uint32_t* rep2s     = (uint32_t*)d_ws;
  uint32_t* rep4s     = rep2s + (size_t)J2 * R2W;
  uint32_t* rep1s     = rep4s + (size_t)J2 * R4W;
  uint32_t* bits      = rep1s + (size_t)J1 * R1W;
  uint2*    pairs     = (uint2*)(bits + WTOT);
  uint32_t* blockSums = (uint32_t*)(pairs + WTOT);
  int*      keys      = (int*)(blockSums + NB1 + 16);

  int nblk = (n + 255) / 256;
  pass_keys<<<nblk, 256, 0, stream>>>(pts, batch, n, keys);
  hist_all<<<256, 1024, 0, stream>>>(batch, keys, n, rep2s, rep4s, rep1s);
  scanA<<<NB1, 256, 0, stream>>>(rep2s, rep4s, rep1s, bits, blockSums);
  scanC<<<NB1, 256, 0, stream>>>(bits, blockSums, pairs);
  epilogue<<<NBLK_INV + NBLK_COORS + NBLK_TAIL, 256, 0, stream>>>(n, pairs, keys, out);
}